// Round 1
// baseline (989.564 us; speedup 1.0000x reference)
//
#include <hip/hip_runtime.h>
#include <cmath>

// ---------------------------------------------------------------------------
// Transformer block, bf16 MFMA implementation.
// B=2, S=2048, D=2048, H=16, HD=128, DFF=8192. M = B*S = 4096 tokens.
//
// Pipeline:
//  1) transpose_cast: W (K x N, fp32) -> Wt (N x K, bf16)  [6 weights]
//  2) ln_kernel: x -> Xln (bf16)
//  3) gemm: QKV = Xln @ [Wq|Wk|Wv]          (M x 6144, bf16)
//  4) attn_kernel: flash attention           -> CTX (M x 2048, bf16)
//  5) gemm: h = x + CTX @ Wo + bo            (fp32)
//  6) ln_kernel: h -> Ln2 (bf16, reuses Xln buffer)
//  7) gemm: Y1 = gelu(Ln2 @ W1 + b1)         (M x 8192, bf16; aliases QKV+CTX)
//  8) gemm: out = h + Y1 @ W2 + b2           (fp32 -> d_out)
// ---------------------------------------------------------------------------

typedef unsigned short u16;
typedef unsigned int   u32;
typedef float  f32x4  __attribute__((ext_vector_type(4)));
typedef short  s16x8  __attribute__((ext_vector_type(8)));
typedef short  s16x4  __attribute__((ext_vector_type(4)));
typedef __bf16 bf16x8 __attribute__((ext_vector_type(8)));

#define DEV __device__ __forceinline__

DEV float bf2f(u16 h) { union { u32 u; float f; } v; v.u = ((u32)h) << 16; return v.f; }
DEV u16 f2bf(float f) {
  union { float f; u32 u; } v; v.f = f;
  u32 u = v.u;
  u += 0x7fffu + ((u >> 16) & 1u);   // round-to-nearest-even
  return (u16)(u >> 16);
}

DEV f32x4 mfma16(s16x8 a, s16x8 b, f32x4 c) {
  return __builtin_amdgcn_mfma_f32_16x16x32_bf16(
      __builtin_bit_cast(bf16x8, a), __builtin_bit_cast(bf16x8, b), c, 0, 0, 0);
}

DEV float gelu_f(float x) {
  const float c = 0.7978845608028654f;  // sqrt(2/pi)
  return 0.5f * x * (1.0f + tanhf(c * (x + 0.044715f * x * x * x)));
}

// ---------------------------------------------------------------------------
// Weight transpose + fp32->bf16 cast.  W: K x N (row-major)  ->  Wt: N x K.
// block (32,8); grid (N/32, K/32).
// ---------------------------------------------------------------------------
__global__ __launch_bounds__(256) void transpose_cast(
    const float* __restrict__ W, u16* __restrict__ Wt, int K, int N) {
  __shared__ float tile[32][33];
  const int n0 = blockIdx.x * 32, k0 = blockIdx.y * 32;
  const int tx = threadIdx.x, ty = threadIdx.y;
#pragma unroll
  for (int i = 0; i < 4; ++i)
    tile[ty + 8 * i][tx] = W[(size_t)(k0 + ty + 8 * i) * N + n0 + tx];
  __syncthreads();
#pragma unroll
  for (int i = 0; i < 4; ++i)
    Wt[(size_t)(n0 + ty + 8 * i) * K + k0 + tx] = f2bf(tile[tx][ty + 8 * i]);
}

// ---------------------------------------------------------------------------
// Row LayerNorm over D=2048, fp32 in -> bf16 out. One block (256 thr) per row.
// ---------------------------------------------------------------------------
__global__ __launch_bounds__(256) void ln_kernel(
    const float* __restrict__ X, const float* __restrict__ sc,
    const float* __restrict__ sh, u16* __restrict__ Y) {
  const int row = blockIdx.x, t = threadIdx.x;
  const float* xr = X + (size_t)row * 2048;
  float4 v0 = ((const float4*)xr)[t];
  float4 v1 = ((const float4*)xr)[t + 256];
  float s  = v0.x + v0.y + v0.z + v0.w + v1.x + v1.y + v1.z + v1.w;
  float qs = v0.x*v0.x + v0.y*v0.y + v0.z*v0.z + v0.w*v0.w
           + v1.x*v1.x + v1.y*v1.y + v1.z*v1.z + v1.w*v1.w;
#pragma unroll
  for (int off = 1; off < 64; off <<= 1) {
    s  += __shfl_xor(s, off);
    qs += __shfl_xor(qs, off);
  }
  __shared__ float rs[4], rq[4];
  if ((t & 63) == 0) { rs[t >> 6] = s; rq[t >> 6] = qs; }
  __syncthreads();
  const float st = rs[0] + rs[1] + rs[2] + rs[3];
  const float qt = rq[0] + rq[1] + rq[2] + rq[3];
  const float mean = st * (1.0f / 2048.0f);
  const float var  = qt * (1.0f / 2048.0f) - mean * mean;
  const float rstd = rsqrtf(var + 1e-5f);

  u16* yr = Y + (size_t)row * 2048;
  const int c0 = t * 4, c1 = 1024 + t * 4;
  s16x4 o0, o1;
  o0[0] = (short)f2bf(sc[c0+0] * (v0.x - mean) * rstd + sh[c0+0]);
  o0[1] = (short)f2bf(sc[c0+1] * (v0.y - mean) * rstd + sh[c0+1]);
  o0[2] = (short)f2bf(sc[c0+2] * (v0.z - mean) * rstd + sh[c0+2]);
  o0[3] = (short)f2bf(sc[c0+3] * (v0.w - mean) * rstd + sh[c0+3]);
  o1[0] = (short)f2bf(sc[c1+0] * (v1.x - mean) * rstd + sh[c1+0]);
  o1[1] = (short)f2bf(sc[c1+1] * (v1.y - mean) * rstd + sh[c1+1]);
  o1[2] = (short)f2bf(sc[c1+2] * (v1.z - mean) * rstd + sh[c1+2]);
  o1[3] = (short)f2bf(sc[c1+3] * (v1.w - mean) * rstd + sh[c1+3]);
  *(s16x4*)(yr + c0) = o0;
  *(s16x4*)(yr + c1) = o1;
}

// ---------------------------------------------------------------------------
// bf16 GEMM: C(MxN) = A(MxK) @ Bt(NxK)^T  [Bt is B transposed, both bf16]
// Tile 128x128, BK=64, 256 threads = 4 waves in 2x2, each wave 64x64 (4x4
// mfma_f32_16x16x32_bf16 frags). Single LDS buffer + register prefetch.
// Epilogue: optional bias (per col), gelu, residual add, fp32 or bf16 store.
// ---------------------------------------------------------------------------
template<int STORE_BF16, int BIAS, int RES, int GELU_ACT>
__global__ __launch_bounds__(256) void gemm_kernel(
    const u16* __restrict__ A, const u16* __restrict__ Bt,
    const float* __restrict__ bias, const float* __restrict__ res,
    float* __restrict__ Cf, u16* __restrict__ Cb,
    int M, int N, int K) {
  __shared__ u16 As[128 * 64];
  __shared__ u16 Bs[128 * 64];
  const int t = threadIdx.x;
  const int lane = t & 63, wave = t >> 6;
  const int row16 = lane & 15, quad = lane >> 4;
  const int wm = wave >> 1, wn = wave & 1;
  const long m0 = (long)blockIdx.y * 128;
  const long n0 = (long)blockIdx.x * 128;

  const u16* Ap = A  + (m0 + (t >> 3)) * (long)K + (t & 7) * 8;
  const u16* Bp = Bt + (n0 + (t >> 3)) * (long)K + (t & 7) * 8;
  u16* AsW = &As[(t >> 3) * 64 + (t & 7) * 8];
  u16* BsW = &Bs[(t >> 3) * 64 + (t & 7) * 8];

  f32x4 acc[4][4] = {};

  s16x8 a_st[4], b_st[4];
#pragma unroll
  for (int i = 0; i < 4; ++i) a_st[i] = *(const s16x8*)(Ap + (long)i * 32 * K);
#pragma unroll
  for (int i = 0; i < 4; ++i) b_st[i] = *(const s16x8*)(Bp + (long)i * 32 * K);

  for (int k0 = 0; k0 < K; k0 += 64) {
    __syncthreads();  // previous iteration's LDS reads complete
#pragma unroll
    for (int i = 0; i < 4; ++i) *(s16x8*)(AsW + i * 32 * 64) = a_st[i];
#pragma unroll
    for (int i = 0; i < 4; ++i) *(s16x8*)(BsW + i * 32 * 64) = b_st[i];
    __syncthreads();

    if (k0 + 64 < K) {  // prefetch next K-tile into regs; overlaps MFMAs below
#pragma unroll
      for (int i = 0; i < 4; ++i) a_st[i] = *(const s16x8*)(Ap + (long)i * 32 * K + k0 + 64);
#pragma unroll
      for (int i = 0; i < 4; ++i) b_st[i] = *(const s16x8*)(Bp + (long)i * 32 * K + k0 + 64);
    }

#pragma unroll
    for (int ks = 0; ks < 2; ++ks) {
      s16x8 af[4], bf_[4];
#pragma unroll
      for (int mi = 0; mi < 4; ++mi)
        af[mi] = *(const s16x8*)&As[(wm * 64 + mi * 16 + row16) * 64 + ks * 32 + quad * 8];
#pragma unroll
      for (int ni = 0; ni < 4; ++ni)
        bf_[ni] = *(const s16x8*)&Bs[(wn * 64 + ni * 16 + row16) * 64 + ks * 32 + quad * 8];
#pragma unroll
      for (int mi = 0; mi < 4; ++mi)
#pragma unroll
        for (int ni = 0; ni < 4; ++ni)
          acc[mi][ni] = mfma16(af[mi], bf_[ni], acc[mi][ni]);
    }
  }

  // Epilogue. C/D frag layout: col = lane&15, row = quad*4 + r  (verified).
#pragma unroll
  for (int mi = 0; mi < 4; ++mi) {
#pragma unroll
    for (int ni = 0; ni < 4; ++ni) {
#pragma unroll
      for (int r = 0; r < 4; ++r) {
        const long gr = m0 + wm * 64 + mi * 16 + quad * 4 + r;
        const long gc = n0 + wn * 64 + ni * 16 + row16;
        float v = acc[mi][ni][r];
        if (BIAS)     v += bias[gc];
        if (GELU_ACT) v  = gelu_f(v);
        if (RES)      v += res[gr * N + gc];
        if (STORE_BF16) Cb[gr * N + gc] = f2bf(v);
        else            Cf[gr * N + gc] = v;
      }
    }
  }
}

// ---------------------------------------------------------------------------
// Causal flash attention. QKV: (B*S) x 6144 bf16 rows [Q|K|V], head h at
// cols h*128.. within each 2048 segment. One wave per (b, h, 16 q-rows).
// Online softmax; P goes through 1KB LDS to become the PV MFMA A operand.
// ---------------------------------------------------------------------------
__global__ __launch_bounds__(64) void attn_kernel(
    const u16* __restrict__ QKV, u16* __restrict__ CTX) {
  const int lane = threadIdx.x;
  const int row16 = lane & 15, quad = lane >> 4;
  const int qt = blockIdx.x, h = blockIdx.y, b = blockIdx.z;
  const int q0 = qt * 16;
  const long LDQ = 6144;
  const u16* Qb = QKV + (long)b * 2048 * LDQ + h * 128;
  const u16* Kb = Qb + 2048;
  const u16* Vb = Qb + 4096;

  s16x8 aq[4];
#pragma unroll
  for (int ks = 0; ks < 4; ++ks)
    aq[ks] = *(const s16x8*)(Qb + (long)(q0 + row16) * LDQ + ks * 32 + quad * 8);

  f32x4 o[8] = {};
  float mrun[4], lrun[4];
#pragma unroll
  for (int r = 0; r < 4; ++r) { mrun[r] = -1e30f; lrun[r] = 0.0f; }

  __shared__ u16 P_lds[16][32];
  const float scale = 0.08838834764831845f;  // 1/sqrt(128)
  const int nkt = (q0 + 15) / 32 + 1;        // 32-wide kv tiles touching k<=q

  for (int kt = 0; kt < nkt; ++kt) {
    const int kbase = kt * 32;
    f32x4 sc[2];
#pragma unroll
    for (int kh = 0; kh < 2; ++kh) {
      f32x4 z = {};
      sc[kh] = z;
#pragma unroll
      for (int ks = 0; ks < 4; ++ks) {
        s16x8 bk = *(const s16x8*)(Kb + (long)(kbase + kh * 16 + row16) * LDQ + ks * 32 + quad * 8);
        sc[kh] = mfma16(aq[ks], bk, sc[kh]);
      }
    }
    __syncthreads();  // prior PV reads of P_lds done before overwrite

    float alpha[4];
#pragma unroll
    for (int r = 0; r < 4; ++r) {
      const int q = q0 + quad * 4 + r;
      float s0 = sc[0][r] * scale; if (kbase + row16 > q)      s0 = -1e30f;
      float s1 = sc[1][r] * scale; if (kbase + 16 + row16 > q) s1 = -1e30f;
      float mx = fmaxf(s0, s1);
#pragma unroll
      for (int off = 1; off < 16; off <<= 1) mx = fmaxf(mx, __shfl_xor(mx, off));
      const float mn = fmaxf(mrun[r], mx);
      alpha[r] = __expf(mrun[r] - mn);
      mrun[r] = mn;
      const float p0 = __expf(s0 - mn);
      const float p1 = __expf(s1 - mn);
      float rsum = p0 + p1;
#pragma unroll
      for (int off = 1; off < 16; off <<= 1) rsum += __shfl_xor(rsum, off);
      lrun[r] = lrun[r] * alpha[r] + rsum;
      P_lds[quad * 4 + r][row16]      = f2bf(p0);
      P_lds[quad * 4 + r][16 + row16] = f2bf(p1);
    }
#pragma unroll
    for (int ds = 0; ds < 8; ++ds)
#pragma unroll
      for (int r = 0; r < 4; ++r) o[ds][r] *= alpha[r];
    __syncthreads();  // P_lds visible

    const s16x8 ap = *(const s16x8*)&P_lds[row16][quad * 8];
#pragma unroll
    for (int ds = 0; ds < 8; ++ds) {
      s16x8 bv;
#pragma unroll
      for (int e = 0; e < 8; ++e)
        bv[e] = (short)Vb[(long)(kbase + quad * 8 + e) * LDQ + ds * 16 + row16];
      o[ds] = mfma16(ap, bv, o[ds]);
    }
  }

#pragma unroll
  for (int ds = 0; ds < 8; ++ds)
#pragma unroll
    for (int r = 0; r < 4; ++r) {
      const float v = o[ds][r] / lrun[r];
      CTX[(long)(b * 2048 + q0 + quad * 4 + r) * 2048 + h * 128 + ds * 16 + row16] = f2bf(v);
    }
}

// ---------------------------------------------------------------------------
extern "C" void kernel_launch(void* const* d_in, const int* in_sizes, int n_in,
                              void* d_out, int out_size, void* d_ws, size_t ws_size,
                              hipStream_t stream) {
  (void)in_sizes; (void)n_in; (void)out_size; (void)ws_size;
  const float* x    = (const float*)d_in[0];
  const float* Wq   = (const float*)d_in[1];
  const float* Wk   = (const float*)d_in[2];
  const float* Wv   = (const float*)d_in[3];
  const float* Wo   = (const float*)d_in[4];
  const float* bo   = (const float*)d_in[5];
  const float* ln1s = (const float*)d_in[6];
  const float* ln1b = (const float*)d_in[7];
  const float* ln2s = (const float*)d_in[8];
  const float* ln2b = (const float*)d_in[9];
  const float* W1   = (const float*)d_in[10];
  const float* b1   = (const float*)d_in[11];
  const float* W2   = (const float*)d_in[12];
  const float* b2   = (const float*)d_in[13];
  float* out = (float*)d_out;

  const int Mtok = 4096, D = 2048, DFF = 8192, NQKV = 6144;

  char* w = (char*)d_ws;
  u16* Wt_qkv = (u16*)w;  w += (size_t)NQKV * D * 2;   // 25.2 MB
  u16* Wt_o   = (u16*)w;  w += (size_t)D * D * 2;      //  8.4 MB
  u16* Wt_1   = (u16*)w;  w += (size_t)DFF * D * 2;    // 33.6 MB
  u16* Wt_2   = (u16*)w;  w += (size_t)D * DFF * 2;    // 33.6 MB
  u16* Xln    = (u16*)w;  w += (size_t)Mtok * D * 2;   // 16.8 MB (reused for Ln2)
  u16* QKV    = (u16*)w;  w += (size_t)Mtok * NQKV * 2;// 50.3 MB
  u16* CTX    = (u16*)w;  w += (size_t)Mtok * D * 2;   // 16.8 MB
  u16* Y1     = QKV;      // Y1 (67.1 MB) aliases QKV+CTX after both are dead
  float* Hbuf = (float*)w; w += (size_t)Mtok * D * 4;  // 33.6 MB
  // total ~208 MiB

  const dim3 tb(32, 8, 1);
  transpose_cast<<<dim3(D / 32, D / 32), tb, 0, stream>>>(Wq, Wt_qkv,                    D, D);
  transpose_cast<<<dim3(D / 32, D / 32), tb, 0, stream>>>(Wk, Wt_qkv + (size_t)D * D,    D, D);
  transpose_cast<<<dim3(D / 32, D / 32), tb, 0, stream>>>(Wv, Wt_qkv + (size_t)2 * D * D,D, D);
  transpose_cast<<<dim3(D / 32, D / 32), tb, 0, stream>>>(Wo, Wt_o,                      D, D);
  transpose_cast<<<dim3(DFF / 32, D / 32), tb, 0, stream>>>(W1, Wt_1,                    D, DFF);
  transpose_cast<<<dim3(D / 32, DFF / 32), tb, 0, stream>>>(W2, Wt_2,                    DFF, D);

  ln_kernel<<<Mtok, 256, 0, stream>>>(x, ln1s, ln1b, Xln);

  gemm_kernel<1, 0, 0, 0><<<dim3(NQKV / 128, Mtok / 128), 256, 0, stream>>>(
      Xln, Wt_qkv, nullptr, nullptr, nullptr, QKV, Mtok, NQKV, D);

  attn_kernel<<<dim3(128, 16, 2), 64, 0, stream>>>(QKV, CTX);

  gemm_kernel<0, 1, 1, 0><<<dim3(D / 128, Mtok / 128), 256, 0, stream>>>(
      CTX, Wt_o, bo, x, Hbuf, nullptr, Mtok, D, D);

  ln_kernel<<<Mtok, 256, 0, stream>>>(Hbuf, ln2s, ln2b, Xln);

  gemm_kernel<1, 1, 0, 1><<<dim3(DFF / 128, Mtok / 128), 256, 0, stream>>>(
      Xln, Wt_1, b1, nullptr, nullptr, Y1, Mtok, DFF, D);

  gemm_kernel<0, 1, 1, 0><<<dim3(D / 128, Mtok / 128), 256, 0, stream>>>(
      Y1, Wt_2, b2, Hbuf, out, nullptr, Mtok, D, DFF);
}

// Round 2
// 926.997 us; speedup vs baseline: 1.0675x; 1.0675x over previous
//
#include <hip/hip_runtime.h>
#include <cmath>

// ---------------------------------------------------------------------------
// Transformer block, bf16 MFMA implementation. B=2,S=2048,D=2048,H=16,HD=128,
// DFF=8192, M=4096 tokens.
// ---------------------------------------------------------------------------

typedef unsigned short u16;
typedef unsigned int   u32;
typedef float  f32x4  __attribute__((ext_vector_type(4)));
typedef short  s16x8  __attribute__((ext_vector_type(8)));
typedef short  s16x4  __attribute__((ext_vector_type(4)));
typedef __bf16 bf16x8 __attribute__((ext_vector_type(8)));

#define DEV __device__ __forceinline__

DEV u16 f2bf(float f) {
  union { float f; u32 u; } v; v.f = f;
  u32 u = v.u;
  u += 0x7fffu + ((u >> 16) & 1u);   // round-to-nearest-even
  return (u16)(u >> 16);
}

DEV f32x4 mfma16(s16x8 a, s16x8 b, f32x4 c) {
  return __builtin_amdgcn_mfma_f32_16x16x32_bf16(
      __builtin_bit_cast(bf16x8, a), __builtin_bit_cast(bf16x8, b), c, 0, 0, 0);
}

DEV float gelu_f(float x) {
  const float c = 0.7978845608028654f;  // sqrt(2/pi)
  return 0.5f * x * (1.0f + tanhf(c * (x + 0.044715f * x * x * x)));
}

// async global->LDS, 16B per lane. Dest must be wave-uniform base + lane*16.
DEV void gload16(const u16* g, u16* l) {
  __builtin_amdgcn_global_load_lds(
      (const __attribute__((address_space(1))) u32*)(const void*)g,
      (__attribute__((address_space(3))) u32*)(void*)l, 16, 0, 0);
}

// ---------------------------------------------------------------------------
// Weight transpose + fp32->bf16 cast.  W: K x N (row-major)  ->  Wt: N x K.
// ---------------------------------------------------------------------------
__global__ __launch_bounds__(256) void transpose_cast(
    const float* __restrict__ W, u16* __restrict__ Wt, int K, int N) {
  __shared__ float tile[32][33];
  const int n0 = blockIdx.x * 32, k0 = blockIdx.y * 32;
  const int tx = threadIdx.x, ty = threadIdx.y;
#pragma unroll
  for (int i = 0; i < 4; ++i)
    tile[ty + 8 * i][tx] = W[(size_t)(k0 + ty + 8 * i) * N + n0 + tx];
  __syncthreads();
#pragma unroll
  for (int i = 0; i < 4; ++i)
    Wt[(size_t)(n0 + ty + 8 * i) * K + k0 + tx] = f2bf(tile[tx][ty + 8 * i]);
}

// ---------------------------------------------------------------------------
// Row LayerNorm over D=2048, fp32 in -> bf16 out. One block (256 thr) per row.
// ---------------------------------------------------------------------------
__global__ __launch_bounds__(256) void ln_kernel(
    const float* __restrict__ X, const float* __restrict__ sc,
    const float* __restrict__ sh, u16* __restrict__ Y) {
  const int row = blockIdx.x, t = threadIdx.x;
  const float* xr = X + (size_t)row * 2048;
  float4 v0 = ((const float4*)xr)[t];
  float4 v1 = ((const float4*)xr)[t + 256];
  float s  = v0.x + v0.y + v0.z + v0.w + v1.x + v1.y + v1.z + v1.w;
  float qs = v0.x*v0.x + v0.y*v0.y + v0.z*v0.z + v0.w*v0.w
           + v1.x*v1.x + v1.y*v1.y + v1.z*v1.z + v1.w*v1.w;
#pragma unroll
  for (int off = 1; off < 64; off <<= 1) {
    s  += __shfl_xor(s, off);
    qs += __shfl_xor(qs, off);
  }
  __shared__ float rs[4], rq[4];
  if ((t & 63) == 0) { rs[t >> 6] = s; rq[t >> 6] = qs; }
  __syncthreads();
  const float st = rs[0] + rs[1] + rs[2] + rs[3];
  const float qt = rq[0] + rq[1] + rq[2] + rq[3];
  const float mean = st * (1.0f / 2048.0f);
  const float var  = qt * (1.0f / 2048.0f) - mean * mean;
  const float rstd = rsqrtf(var + 1e-5f);

  u16* yr = Y + (size_t)row * 2048;
  const int c0 = t * 4, c1 = 1024 + t * 4;
  s16x4 o0, o1;
  o0[0] = (short)f2bf(sc[c0+0] * (v0.x - mean) * rstd + sh[c0+0]);
  o0[1] = (short)f2bf(sc[c0+1] * (v0.y - mean) * rstd + sh[c0+1]);
  o0[2] = (short)f2bf(sc[c0+2] * (v0.z - mean) * rstd + sh[c0+2]);
  o0[3] = (short)f2bf(sc[c0+3] * (v0.w - mean) * rstd + sh[c0+3]);
  o1[0] = (short)f2bf(sc[c1+0] * (v1.x - mean) * rstd + sh[c1+0]);
  o1[1] = (short)f2bf(sc[c1+1] * (v1.y - mean) * rstd + sh[c1+1]);
  o1[2] = (short)f2bf(sc[c1+2] * (v1.z - mean) * rstd + sh[c1+2]);
  o1[3] = (short)f2bf(sc[c1+3] * (v1.w - mean) * rstd + sh[c1+3]);
  *(s16x4*)(yr + c0) = o0;
  *(s16x4*)(yr + c1) = o1;
}

// ---------------------------------------------------------------------------
// bf16 GEMM: C(MxN) = A(MxK) @ Bt(NxK)^T. Tile 128x128, BK=64, 4 waves 2x2.
// m97 structure: global_load_lds width-16 staging, single LDS buffer,
// 2 barriers per K-step.
// ---------------------------------------------------------------------------
template<int STORE_BF16, int BIAS, int RES, int GELU_ACT>
__global__ __launch_bounds__(256) void gemm_kernel(
    const u16* __restrict__ A, const u16* __restrict__ Bt,
    const float* __restrict__ bias, const float* __restrict__ res,
    float* __restrict__ Cf, u16* __restrict__ Cb,
    int M, int N, int K) {
  __shared__ u16 As[128 * 64];
  __shared__ u16 Bs[128 * 64];
  const int t = threadIdx.x;
  const int lane = t & 63, wave = t >> 6;
  const int row16 = lane & 15, quad = lane >> 4;
  const int wm = wave >> 1, wn = wave & 1;
  const long m0 = (long)blockIdx.y * 128;
  const long n0 = (long)blockIdx.x * 128;

  // staging map: thread t covers (row = i*32 + (t>>3), col8 = t&7);
  // LDS linear byte off = i*4096 + wave*1024 + lane*16 (global_load_lds-legal)
  const u16* Ag = A  + (m0 + (t >> 3)) * (long)K + (t & 7) * 8;
  const u16* Bg = Bt + (n0 + (t >> 3)) * (long)K + (t & 7) * 8;
  u16* AsD = As + wave * 512;   // wave-uniform dest base (u16 units)
  u16* BsD = Bs + wave * 512;

  f32x4 acc[4][4] = {};

  for (int k0 = 0; k0 < K; k0 += 64) {
    __syncthreads();  // previous iteration's LDS reads complete
#pragma unroll
    for (int i = 0; i < 4; ++i) gload16(Ag + (long)i * 32 * K + k0, AsD + i * 2048);
#pragma unroll
    for (int i = 0; i < 4; ++i) gload16(Bg + (long)i * 32 * K + k0, BsD + i * 2048);
    __syncthreads();  // compiler drains vmcnt before barrier

#pragma unroll
    for (int ks = 0; ks < 2; ++ks) {
      s16x8 af[4], bf_[4];
#pragma unroll
      for (int mi = 0; mi < 4; ++mi)
        af[mi] = *(const s16x8*)&As[(wm * 64 + mi * 16 + row16) * 64 + ks * 32 + quad * 8];
#pragma unroll
      for (int ni = 0; ni < 4; ++ni)
        bf_[ni] = *(const s16x8*)&Bs[(wn * 64 + ni * 16 + row16) * 64 + ks * 32 + quad * 8];
#pragma unroll
      for (int mi = 0; mi < 4; ++mi)
#pragma unroll
        for (int ni = 0; ni < 4; ++ni)
          acc[mi][ni] = mfma16(af[mi], bf_[ni], acc[mi][ni]);
    }
  }

  // Epilogue. C/D frag layout: col = lane&15, row = quad*4 + r.
#pragma unroll
  for (int mi = 0; mi < 4; ++mi) {
#pragma unroll
    for (int ni = 0; ni < 4; ++ni) {
#pragma unroll
      for (int r = 0; r < 4; ++r) {
        const long gr = m0 + wm * 64 + mi * 16 + quad * 4 + r;
        const long gc = n0 + wn * 64 + ni * 16 + row16;
        float v = acc[mi][ni][r];
        if (BIAS)     v += bias[gc];
        if (GELU_ACT) v  = gelu_f(v);
        if (RES)      v += res[gr * N + gc];
        if (STORE_BF16) Cb[gr * N + gc] = f2bf(v);
        else            Cf[gr * N + gc] = v;
      }
    }
  }
}

// ---------------------------------------------------------------------------
// Causal flash attention, 4 waves/block, QBLK=64 (16 q-rows per wave),
// KVBLK=64. K staged via global_load_lds (pre-swizzled source), V staged
// transposed in LDS (swizzled), P via per-wave swizzled LDS.
// Blocks process q-tile pair {p, 31-p} for load balance (33 tiles each).
// Swizzle everywhere: u16_idx ^= ((row&7)<<3)  (16B-slot XOR within row).
// ---------------------------------------------------------------------------
__global__ __launch_bounds__(256) void attn_kernel(
    const u16* __restrict__ QKV, u16* __restrict__ CTX) {
  __shared__ u16 Ks[64 * 128];     // [kv][d]
  __shared__ u16 Vt[128 * 64];     // [d][kv]
  __shared__ u16 Pl[4 * 16 * 64];  // per-wave [q][kv]

  const int t = threadIdx.x;
  const int lane = t & 63, w = t >> 6;
  const int r16 = lane & 15, quad = lane >> 4;
  const int h = blockIdx.y, b = blockIdx.z;
  const long LDQ = 6144;
  const u16* Qb = QKV + (long)b * 2048 * LDQ + h * 128;
  const u16* Kb = Qb + 2048;
  const u16* Vb = Qb + 4096;
  u16* Pw = Pl + w * (16 * 64);

  const int srow = t >> 4;    // 0..15 (staging row within 16-row chunk)
  const int sslot = t & 15;   // 16B slot within 128-col row
  const float scale = 0.08838834764831845f;  // 1/sqrt(128)

  for (int half = 0; half < 2; ++half) {
    const int qt = half ? (31 - (int)blockIdx.x) : (int)blockIdx.x;
    const int q0 = qt * 64;
    const int qw = q0 + w * 16;

    s16x8 aq[4];
#pragma unroll
    for (int ks = 0; ks < 4; ++ks)
      aq[ks] = *(const s16x8*)(Qb + (long)(qw + r16) * LDQ + ks * 32 + quad * 8);

    f32x4 o[8] = {};
    float mrun[4], lrun[4];
#pragma unroll
    for (int r = 0; r < 4; ++r) { mrun[r] = -1e30f; lrun[r] = 0.0f; }

    for (int kt = 0; kt <= qt; ++kt) {
      const int kbase = kt * 64;
      __syncthreads();  // prior tile's LDS reads complete

      // --- stage K: global_load_lds, linear dest, pre-swizzled source ---
#pragma unroll
      for (int i = 0; i < 4; ++i) {
        const int row = i * 16 + srow;
        const int gslot = sslot ^ (row & 7);
        gload16(Kb + (long)(kbase + row) * LDQ + gslot * 8,
                Ks + i * 2048 + w * 512);
      }
      // --- stage V transposed: reg load + rotated swizzled b16 writes ---
      s16x8 vv[4];
#pragma unroll
      for (int i = 0; i < 4; ++i)
        vv[i] = *(const s16x8*)(Vb + (long)(kbase + i * 16 + srow) * LDQ + sslot * 8);
#pragma unroll
      for (int i = 0; i < 4; ++i) {
        const int k = i * 16 + srow;
#pragma unroll
        for (int j = 0; j < 8; ++j) {
          const int e = (j + (t & 7)) & 7;
          const int d = sslot * 8 + e;
          Vt[(d * 64 + k) ^ ((d & 7) << 3)] = (u16)vv[i][e];
        }
      }
      __syncthreads();  // K (vmcnt) + Vt (lgkm) visible to all waves

      // --- QK^T: S[16q x 64kv] per wave ---
      f32x4 sc[4];
#pragma unroll
      for (int kh = 0; kh < 4; ++kh) {
        f32x4 z = {};
        sc[kh] = z;
        const int krow = kh * 16 + r16;
#pragma unroll
        for (int ks = 0; ks < 4; ++ks) {
          s16x8 bk = *(const s16x8*)&Ks[(krow * 128 + ks * 32 + quad * 8) ^ ((krow & 7) << 3)];
          sc[kh] = mfma16(aq[ks], bk, sc[kh]);
        }
      }

      // --- online softmax (per lane: 4 q-rows, 4 kv-cols each frag) ---
      float alpha[4];
#pragma unroll
      for (int r = 0; r < 4; ++r) {
        const int q = qw + quad * 4 + r;
        float sv[4];
#pragma unroll
        for (int kh = 0; kh < 4; ++kh) {
          float s = sc[kh][r] * scale;
          if (kbase + kh * 16 + r16 > q) s = -1e30f;
          sv[kh] = s;
        }
        float mx = fmaxf(fmaxf(sv[0], sv[1]), fmaxf(sv[2], sv[3]));
#pragma unroll
        for (int off = 1; off < 16; off <<= 1) mx = fmaxf(mx, __shfl_xor(mx, off));
        const float mn = fmaxf(mrun[r], mx);
        alpha[r] = __expf(mrun[r] - mn);
        mrun[r] = mn;
        float rsum = 0.0f;
        const int prow = quad * 4 + r;
#pragma unroll
        for (int kh = 0; kh < 4; ++kh) {
          const float p = __expf(sv[kh] - mn);
          rsum += p;
          Pw[(prow * 64 + kh * 16 + r16) ^ ((prow & 7) << 3)] = f2bf(p);
        }
#pragma unroll
        for (int off = 1; off < 16; off <<= 1) rsum += __shfl_xor(rsum, off);
        lrun[r] = lrun[r] * alpha[r] + rsum;
      }
#pragma unroll
      for (int ds = 0; ds < 8; ++ds)
#pragma unroll
        for (int r = 0; r < 4; ++r) o[ds][r] *= alpha[r];

      // --- PV: o[16q x 128d] += P[16x64] @ V[64x128] ---
#pragma unroll
      for (int s = 0; s < 2; ++s) {
        const s16x8 ap = *(const s16x8*)&Pw[(r16 * 64 + s * 32 + quad * 8) ^ ((r16 & 7) << 3)];
#pragma unroll
        for (int ds = 0; ds < 8; ++ds) {
          const int d = ds * 16 + r16;
          s16x8 bv = *(const s16x8*)&Vt[(d * 64 + s * 32 + quad * 8) ^ ((d & 7) << 3)];
          o[ds] = mfma16(ap, bv, o[ds]);
        }
      }
    }

    // --- epilogue for this q-tile ---
#pragma unroll
    for (int ds = 0; ds < 8; ++ds)
#pragma unroll
      for (int r = 0; r < 4; ++r) {
        const float v = o[ds][r] / lrun[r];
        CTX[(long)(b * 2048 + qw + quad * 4 + r) * 2048 + h * 128 + ds * 16 + r16] = f2bf(v);
      }
  }
}

// ---------------------------------------------------------------------------
extern "C" void kernel_launch(void* const* d_in, const int* in_sizes, int n_in,
                              void* d_out, int out_size, void* d_ws, size_t ws_size,
                              hipStream_t stream) {
  (void)in_sizes; (void)n_in; (void)out_size; (void)ws_size;
  const float* x    = (const float*)d_in[0];
  const float* Wq   = (const float*)d_in[1];
  const float* Wk   = (const float*)d_in[2];
  const float* Wv   = (const float*)d_in[3];
  const float* Wo   = (const float*)d_in[4];
  const float* bo   = (const float*)d_in[5];
  const float* ln1s = (const float*)d_in[6];
  const float* ln1b = (const float*)d_in[7];
  const float* ln2s = (const float*)d_in[8];
  const float* ln2b = (const float*)d_in[9];
  const float* W1   = (const float*)d_in[10];
  const float* b1   = (const float*)d_in[11];
  const float* W2   = (const float*)d_in[12];
  const float* b2   = (const float*)d_in[13];
  float* out = (float*)d_out;

  const int Mtok = 4096, D = 2048, DFF = 8192, NQKV = 6144;

  char* w = (char*)d_ws;
  u16* Wt_qkv = (u16*)w;  w += (size_t)NQKV * D * 2;
  u16* Wt_o   = (u16*)w;  w += (size_t)D * D * 2;
  u16* Wt_1   = (u16*)w;  w += (size_t)DFF * D * 2;
  u16* Wt_2   = (u16*)w;  w += (size_t)D * DFF * 2;
  u16* Xln    = (u16*)w;  w += (size_t)Mtok * D * 2;
  u16* QKV    = (u16*)w;  w += (size_t)Mtok * NQKV * 2;
  u16* CTX    = (u16*)w;  w += (size_t)Mtok * D * 2;
  u16* Y1     = QKV;      // aliases QKV+CTX after both are dead
  float* Hbuf = (float*)w; w += (size_t)Mtok * D * 4;

  const dim3 tb(32, 8, 1);
  transpose_cast<<<dim3(D / 32, D / 32), tb, 0, stream>>>(Wq, Wt_qkv,                    D, D);
  transpose_cast<<<dim3(D / 32, D / 32), tb, 0, stream>>>(Wk, Wt_qkv + (size_t)D * D,    D, D);
  transpose_cast<<<dim3(D / 32, D / 32), tb, 0, stream>>>(Wv, Wt_qkv + (size_t)2 * D * D,D, D);
  transpose_cast<<<dim3(D / 32, D / 32), tb, 0, stream>>>(Wo, Wt_o,                      D, D);
  transpose_cast<<<dim3(DFF / 32, D / 32), tb, 0, stream>>>(W1, Wt_1,                    D, DFF);
  transpose_cast<<<dim3(D / 32, DFF / 32), tb, 0, stream>>>(W2, Wt_2,                    DFF, D);

  ln_kernel<<<Mtok, 256, 0, stream>>>(x, ln1s, ln1b, Xln);

  gemm_kernel<1, 0, 0, 0><<<dim3(NQKV / 128, Mtok / 128), 256, 0, stream>>>(
      Xln, Wt_qkv, nullptr, nullptr, nullptr, QKV, Mtok, NQKV, D);

  attn_kernel<<<dim3(16, 16, 2), 256, 0, stream>>>(QKV, CTX);

  gemm_kernel<0, 1, 1, 0><<<dim3(D / 128, Mtok / 128), 256, 0, stream>>>(
      CTX, Wt_o, bo, x, Hbuf, nullptr, Mtok, D, D);

  ln_kernel<<<Mtok, 256, 0, stream>>>(Hbuf, ln2s, ln2b, Xln);

  gemm_kernel<1, 1, 0, 1><<<dim3(DFF / 128, Mtok / 128), 256, 0, stream>>>(
      Xln, Wt_1, b1, nullptr, nullptr, Y1, Mtok, DFF, D);

  gemm_kernel<0, 1, 1, 0><<<dim3(D / 128, Mtok / 128), 256, 0, stream>>>(
      Y1, Wt_2, b2, Hbuf, out, nullptr, Mtok, D, DFF);
}

// Round 3
// 714.092 us; speedup vs baseline: 1.3858x; 1.2981x over previous
//
#include <hip/hip_runtime.h>
#include <cmath>

// ---------------------------------------------------------------------------
// Transformer block, bf16 MFMA. B=2,S=2048,D=2048,H=16,HD=128,DFF=8192,M=4096.
// GEMMs use an 8-phase-style interleaved schedule (T2 swizzle + T3/T4 counted
// vmcnt + T5 setprio), 512 threads = 8 waves (2M x 4N), BK=64.
// ---------------------------------------------------------------------------

typedef unsigned short u16;
typedef unsigned int   u32;
typedef float  f32x4  __attribute__((ext_vector_type(4)));
typedef short  s16x8  __attribute__((ext_vector_type(8)));
typedef short  s16x4  __attribute__((ext_vector_type(4)));
typedef __bf16 bf16x8 __attribute__((ext_vector_type(8)));

#define DEV __device__ __forceinline__

DEV u16 f2bf(float f) {
  union { float f; u32 u; } v; v.f = f;
  u32 u = v.u;
  u += 0x7fffu + ((u >> 16) & 1u);   // round-to-nearest-even
  return (u16)(u >> 16);
}

DEV f32x4 mfma16(s16x8 a, s16x8 b, f32x4 c) {
  return __builtin_amdgcn_mfma_f32_16x16x32_bf16(
      __builtin_bit_cast(bf16x8, a), __builtin_bit_cast(bf16x8, b), c, 0, 0, 0);
}

DEV float gelu_f(float x) {
  const float c = 0.7978845608028654f;  // sqrt(2/pi)
  return 0.5f * x * (1.0f + tanhf(c * (x + 0.044715f * x * x * x)));
}

// async global->LDS, 16B per lane. Dest is wave-uniform base + lane*16.
DEV void gload16(const u16* g, u16* l) {
  __builtin_amdgcn_global_load_lds(
      (const __attribute__((address_space(1))) u32*)(const void*)g,
      (__attribute__((address_space(3))) u32*)(void*)l, 16, 0, 0);
}

// ---------------------------------------------------------------------------
// Weight transpose + fp32->bf16 cast.  W: K x N (row-major)  ->  Wt: N x K.
// ---------------------------------------------------------------------------
__global__ __launch_bounds__(256) void transpose_cast(
    const float* __restrict__ W, u16* __restrict__ Wt, int K, int N) {
  __shared__ float tile[32][33];
  const int n0 = blockIdx.x * 32, k0 = blockIdx.y * 32;
  const int tx = threadIdx.x, ty = threadIdx.y;
#pragma unroll
  for (int i = 0; i < 4; ++i)
    tile[ty + 8 * i][tx] = W[(size_t)(k0 + ty + 8 * i) * N + n0 + tx];
  __syncthreads();
#pragma unroll
  for (int i = 0; i < 4; ++i)
    Wt[(size_t)(n0 + ty + 8 * i) * K + k0 + tx] = f2bf(tile[tx][ty + 8 * i]);
}

// ---------------------------------------------------------------------------
// Row LayerNorm over D=2048, fp32 in -> bf16 out. One block (256 thr) per row.
// ---------------------------------------------------------------------------
__global__ __launch_bounds__(256) void ln_kernel(
    const float* __restrict__ X, const float* __restrict__ sc,
    const float* __restrict__ sh, u16* __restrict__ Y) {
  const int row = blockIdx.x, t = threadIdx.x;
  const float* xr = X + (size_t)row * 2048;
  float4 v0 = ((const float4*)xr)[t];
  float4 v1 = ((const float4*)xr)[t + 256];
  float s  = v0.x + v0.y + v0.z + v0.w + v1.x + v1.y + v1.z + v1.w;
  float qs = v0.x*v0.x + v0.y*v0.y + v0.z*v0.z + v0.w*v0.w
           + v1.x*v1.x + v1.y*v1.y + v1.z*v1.z + v1.w*v1.w;
#pragma unroll
  for (int off = 1; off < 64; off <<= 1) {
    s  += __shfl_xor(s, off);
    qs += __shfl_xor(qs, off);
  }
  __shared__ float rs[4], rq[4];
  if ((t & 63) == 0) { rs[t >> 6] = s; rq[t >> 6] = qs; }
  __syncthreads();
  const float st = rs[0] + rs[1] + rs[2] + rs[3];
  const float qt = rq[0] + rq[1] + rq[2] + rq[3];
  const float mean = st * (1.0f / 2048.0f);
  const float var  = qt * (1.0f / 2048.0f) - mean * mean;
  const float rstd = rsqrtf(var + 1e-5f);

  u16* yr = Y + (size_t)row * 2048;
  const int c0 = t * 4, c1 = 1024 + t * 4;
  s16x4 o0, o1;
  o0[0] = (short)f2bf(sc[c0+0] * (v0.x - mean) * rstd + sh[c0+0]);
  o0[1] = (short)f2bf(sc[c0+1] * (v0.y - mean) * rstd + sh[c0+1]);
  o0[2] = (short)f2bf(sc[c0+2] * (v0.z - mean) * rstd + sh[c0+2]);
  o0[3] = (short)f2bf(sc[c0+3] * (v0.w - mean) * rstd + sh[c0+3]);
  o1[0] = (short)f2bf(sc[c1+0] * (v1.x - mean) * rstd + sh[c1+0]);
  o1[1] = (short)f2bf(sc[c1+1] * (v1.y - mean) * rstd + sh[c1+1]);
  o1[2] = (short)f2bf(sc[c1+2] * (v1.z - mean) * rstd + sh[c1+2]);
  o1[3] = (short)f2bf(sc[c1+3] * (v1.w - mean) * rstd + sh[c1+3]);
  *(s16x4*)(yr + c0) = o0;
  *(s16x4*)(yr + c1) = o1;
}

// ---------------------------------------------------------------------------
// Phase-interleaved GEMM: C(MxN) = A(MxK) @ Bt(NxK)^T, bf16 in, BK=64.
// 512 thr = 8 waves (2M x 4N). BN=256 always. BM = 128*MHALF.
//  MHALF=2: per-wave 128x64, acc[8][4]; LDS 2 K-tile bufs (A 2x16KB + B 2x32KB
//           = 128KB); stage A(t+1)@ph0/1, B(t+2)@ph2/3; vmcnt(4) per tile.
//  MHALF=1: per-wave 64x64, acc[4][4];  LDS A 3x16KB + B 2x32KB = 112KB;
//           stage A(t+2)@ph0, B(t+2)@ph1; vmcnt(6) per tile.
// LDS XOR-swizzle: 16B-slot ^= (row&7), applied via pre-swizzled global source
// (linear gload dest) and matching XOR on ds_read (both-sides-or-neither).
// Every stage targets a region whose last reader finished >=1 barrier earlier.
// ---------------------------------------------------------------------------
template<int MHALF, int STORE_BF16, int BIAS, int RES, int GELU_ACT>
__global__ __launch_bounds__(512, 2) void gemm8(
    const u16* __restrict__ A, const u16* __restrict__ Bt,
    const float* __restrict__ bias, const float* __restrict__ res,
    float* __restrict__ Cf, u16* __restrict__ Cb,
    int M, int N, int K) {
  constexpr int NPH   = 2 * MHALF;          // phases per K-tile
  constexpr int ABUFS = (MHALF == 2) ? 2 : 3;
  constexpr int ASZ   = 8192 * MHALF;       // u16 per A buffer
  constexpr int BOFF  = ABUFS * ASZ;        // B region base (u16)
  __shared__ u16 lds[BOFF + 2 * 16384];     // 128KB (MHALF=2) / 112KB (MHALF=1)

  const int t9 = threadIdx.x;
  const int l = t9 & 63, w = t9 >> 6;
  const int r16 = l & 15, quad = l >> 4;
  const int wm = w >> 2, wn = w & 3;

  // XCD-aware swizzle (grids are multiples of 8)
  const int nbx = N >> 8;
  const int nwg = gridDim.x;
  const int cpx = nwg >> 3;
  const int bid = blockIdx.x;
  const int swz = (bid & 7) * cpx + (bid >> 3);
  const long m0 = (long)(swz / nbx) * (128 * MHALF);
  const long n0 = (long)(swz % nbx) * 256;

  const int NT = K >> 6;
  const int srow = t9 >> 3;                    // 0..63
  const int scol = (t9 & 7) ^ (srow & 7);      // pre-swizzled 16B slot

  const u16* Abase = A  + (m0 + srow) * (long)K + scol * 8;
  const u16* Bbase = Bt + (n0 + srow) * (long)K + scol * 8;
  const long rowK64  = 64 * (long)K;
  const long rowK128 = 128 * (long)K;

  // stage half-tile h (128 rows x 64 cols) of A/B K-tile `tile`
  #define STAGE_A(tile, h) { \
    u16* d = &lds[((tile) % ABUFS) * ASZ + (h) * 8192 + w * 512]; \
    const u16* s = Abase + (h) * rowK128 + (long)(tile) * 64; \
    gload16(s, d); gload16(s + rowK64, d + 4096); }
  #define STAGE_B(tile, h) { \
    u16* d = &lds[BOFF + ((tile) & 1) * 16384 + (h) * 8192 + w * 512]; \
    const u16* s = Bbase + (h) * rowK128 + (long)(tile) * 64; \
    gload16(s, d); gload16(s + rowK64, d + 4096); }

  f32x4 acc[4 * MHALF][4] = {};

  // prologue: tile0 fully + next A (+ next B for MHALF=1)
  if (MHALF == 2) {
    STAGE_B(0, 0); STAGE_B(0, 1); STAGE_A(0, 0); STAGE_A(0, 1);
    STAGE_B(1, 0); STAGE_B(1, 1);
    asm volatile("s_waitcnt vmcnt(4)" ::: "memory");
  } else {
    STAGE_B(0, 0); STAGE_B(0, 1); STAGE_A(0, 0); STAGE_A(1, 0);
    STAGE_B(1, 0); STAGE_B(1, 1);
    asm volatile("s_waitcnt vmcnt(6)" ::: "memory");
  }
  __builtin_amdgcn_sched_barrier(0);
  __builtin_amdgcn_s_barrier();

  s16x8 bf_[4][2];
  for (int t = 0; t < NT; ++t) {
    const int ab = t % ABUFS;
    const u16* Abuf = &lds[ab * ASZ];
    const u16* Bbuf = &lds[BOFF + (t & 1) * 16384];
#pragma unroll
    for (int p = 0; p < NPH; ++p) {
      // ---- ds_read register subtiles ----
      if (p == 0) {
#pragma unroll
        for (int ni = 0; ni < 4; ++ni) {
          const int brow = wn * 64 + ni * 16 + r16;
#pragma unroll
          for (int ks = 0; ks < 2; ++ks)
            bf_[ni][ks] = *(const s16x8*)&Bbuf[brow * 64 + ((ks * 4 + quad) ^ (brow & 7)) * 8];
        }
      }
      s16x8 af[2][2];
#pragma unroll
      for (int mi = 0; mi < 2; ++mi) {
        const int arow = (MHALF == 2 ? wm * 128 : wm * 64) + (2 * p + mi) * 16 + r16;
#pragma unroll
        for (int ks = 0; ks < 2; ++ks)
          af[mi][ks] = *(const s16x8*)&Abuf[arow * 64 + ((ks * 4 + quad) ^ (arow & 7)) * 8];
      }
      // ---- stage prefetch (into provably-dead LDS regions) ----
      if (MHALF == 2) {
        if (p < 2)       { if (t + 1 < NT) STAGE_A(t + 1, p); }
        else             { if (t + 2 < NT) STAGE_B(t + 2, p - 2); }
      } else {
        if (p == 0)      { if (t + 2 < NT) STAGE_A(t + 2, 0); }
        else             { if (t + 2 < NT) { STAGE_B(t + 2, 0); STAGE_B(t + 2, 1); } }
      }
      __builtin_amdgcn_sched_barrier(0);
      __builtin_amdgcn_s_barrier();
      asm volatile("s_waitcnt lgkmcnt(0)" ::: "memory");
      __builtin_amdgcn_sched_barrier(0);
      __builtin_amdgcn_s_setprio(1);
#pragma unroll
      for (int mi = 0; mi < 2; ++mi)
#pragma unroll
        for (int ni = 0; ni < 4; ++ni)
#pragma unroll
          for (int ks = 0; ks < 2; ++ks)
            acc[2 * p + mi][ni] = mfma16(af[mi][ks], bf_[ni][ks], acc[2 * p + mi][ni]);
      __builtin_amdgcn_s_setprio(0);
      __builtin_amdgcn_sched_barrier(0);
      if (p == NPH - 1) {
        // counted waits: remaining outstanding = stages for tiles > t+1
        if (MHALF == 2) {
          if (t + 2 < NT) { asm volatile("s_waitcnt vmcnt(4)" ::: "memory"); }
          else            { asm volatile("s_waitcnt vmcnt(0)" ::: "memory"); }
        } else {
          if (t + 2 < NT) { asm volatile("s_waitcnt vmcnt(6)" ::: "memory"); }
          else            { asm volatile("s_waitcnt vmcnt(0)" ::: "memory"); }
        }
        __builtin_amdgcn_sched_barrier(0);
      }
      __builtin_amdgcn_s_barrier();
    }
  }
  #undef STAGE_A
  #undef STAGE_B

  // Epilogue. C/D frag: col = lane&15, row = quad*4 + r.
#pragma unroll
  for (int mi = 0; mi < 4 * MHALF; ++mi) {
#pragma unroll
    for (int ni = 0; ni < 4; ++ni) {
#pragma unroll
      for (int r = 0; r < 4; ++r) {
        const long gr = m0 + (MHALF == 2 ? wm * 128 : wm * 64) + mi * 16 + quad * 4 + r;
        const long gc = n0 + wn * 64 + ni * 16 + r16;
        float v = acc[mi][ni][r];
        if (BIAS)     v += bias[gc];
        if (GELU_ACT) v  = gelu_f(v);
        if (RES)      v += res[gr * N + gc];
        if (STORE_BF16) Cb[gr * N + gc] = f2bf(v);
        else            Cf[gr * N + gc] = v;
      }
    }
  }
}

// ---------------------------------------------------------------------------
// Causal flash attention, 4 waves/block, QBLK=64, KVBLK=64 (unchanged, R2).
// ---------------------------------------------------------------------------
__global__ __launch_bounds__(256) void attn_kernel(
    const u16* __restrict__ QKV, u16* __restrict__ CTX) {
  __shared__ u16 Ks[64 * 128];     // [kv][d]
  __shared__ u16 Vt[128 * 64];     // [d][kv]
  __shared__ u16 Pl[4 * 16 * 64];  // per-wave [q][kv]

  const int t = threadIdx.x;
  const int lane = t & 63, w = t >> 6;
  const int r16 = lane & 15, quad = lane >> 4;
  const int h = blockIdx.y, b = blockIdx.z;
  const long LDQ = 6144;
  const u16* Qb = QKV + (long)b * 2048 * LDQ + h * 128;
  const u16* Kb = Qb + 2048;
  const u16* Vb = Qb + 4096;
  u16* Pw = Pl + w * (16 * 64);

  const int srow = t >> 4;
  const int sslot = t & 15;
  const float scale = 0.08838834764831845f;  // 1/sqrt(128)

  for (int half = 0; half < 2; ++half) {
    const int qt = half ? (31 - (int)blockIdx.x) : (int)blockIdx.x;
    const int q0 = qt * 64;
    const int qw = q0 + w * 16;

    s16x8 aq[4];
#pragma unroll
    for (int ks = 0; ks < 4; ++ks)
      aq[ks] = *(const s16x8*)(Qb + (long)(qw + r16) * LDQ + ks * 32 + quad * 8);

    f32x4 o[8] = {};
    float mrun[4], lrun[4];
#pragma unroll
    for (int r = 0; r < 4; ++r) { mrun[r] = -1e30f; lrun[r] = 0.0f; }

    for (int kt = 0; kt <= qt; ++kt) {
      const int kbase = kt * 64;
      __syncthreads();

#pragma unroll
      for (int i = 0; i < 4; ++i) {
        const int row = i * 16 + srow;
        const int gslot = sslot ^ (row & 7);
        gload16(Kb + (long)(kbase + row) * LDQ + gslot * 8,
                Ks + i * 2048 + w * 512);
      }
      s16x8 vv[4];
#pragma unroll
      for (int i = 0; i < 4; ++i)
        vv[i] = *(const s16x8*)(Vb + (long)(kbase + i * 16 + srow) * LDQ + sslot * 8);
#pragma unroll
      for (int i = 0; i < 4; ++i) {
        const int k = i * 16 + srow;
#pragma unroll
        for (int j = 0; j < 8; ++j) {
          const int e = (j + (t & 7)) & 7;
          const int d = sslot * 8 + e;
          Vt[(d * 64 + k) ^ ((d & 7) << 3)] = (u16)vv[i][e];
        }
      }
      __syncthreads();

      f32x4 sc[4];
#pragma unroll
      for (int kh = 0; kh < 4; ++kh) {
        f32x4 z = {};
        sc[kh] = z;
        const int krow = kh * 16 + r16;
#pragma unroll
        for (int ks = 0; ks < 4; ++ks) {
          s16x8 bk = *(const s16x8*)&Ks[(krow * 128 + ks * 32 + quad * 8) ^ ((krow & 7) << 3)];
          sc[kh] = mfma16(aq[ks], bk, sc[kh]);
        }
      }

      float alpha[4];
#pragma unroll
      for (int r = 0; r < 4; ++r) {
        const int q = qw + quad * 4 + r;
        float sv[4];
#pragma unroll
        for (int kh = 0; kh < 4; ++kh) {
          float s = sc[kh][r] * scale;
          if (kbase + kh * 16 + r16 > q) s = -1e30f;
          sv[kh] = s;
        }
        float mx = fmaxf(fmaxf(sv[0], sv[1]), fmaxf(sv[2], sv[3]));
#pragma unroll
        for (int off = 1; off < 16; off <<= 1) mx = fmaxf(mx, __shfl_xor(mx, off));
        const float mn = fmaxf(mrun[r], mx);
        alpha[r] = __expf(mrun[r] - mn);
        mrun[r] = mn;
        float rsum = 0.0f;
        const int prow = quad * 4 + r;
#pragma unroll
        for (int kh = 0; kh < 4; ++kh) {
          const float p = __expf(sv[kh] - mn);
          rsum += p;
          Pw[(prow * 64 + kh * 16 + r16) ^ ((prow & 7) << 3)] = f2bf(p);
        }
#pragma unroll
        for (int off = 1; off < 16; off <<= 1) rsum += __shfl_xor(rsum, off);
        lrun[r] = lrun[r] * alpha[r] + rsum;
      }
#pragma unroll
      for (int ds = 0; ds < 8; ++ds)
#pragma unroll
        for (int r = 0; r < 4; ++r) o[ds][r] *= alpha[r];

#pragma unroll
      for (int s = 0; s < 2; ++s) {
        const s16x8 ap = *(const s16x8*)&Pw[(r16 * 64 + s * 32 + quad * 8) ^ ((r16 & 7) << 3)];
#pragma unroll
        for (int ds = 0; ds < 8; ++ds) {
          const int d = ds * 16 + r16;
          s16x8 bv = *(const s16x8*)&Vt[(d * 64 + s * 32 + quad * 8) ^ ((d & 7) << 3)];
          o[ds] = mfma16(ap, bv, o[ds]);
        }
      }
    }

#pragma unroll
    for (int ds = 0; ds < 8; ++ds)
#pragma unroll
      for (int r = 0; r < 4; ++r) {
        const float v = o[ds][r] / lrun[r];
        CTX[(long)(b * 2048 + qw + quad * 4 + r) * 2048 + h * 128 + ds * 16 + r16] = f2bf(v);
      }
  }
}

// ---------------------------------------------------------------------------
extern "C" void kernel_launch(void* const* d_in, const int* in_sizes, int n_in,
                              void* d_out, int out_size, void* d_ws, size_t ws_size,
                              hipStream_t stream) {
  (void)in_sizes; (void)n_in; (void)out_size; (void)ws_size;
  const float* x    = (const float*)d_in[0];
  const float* Wq   = (const float*)d_in[1];
  const float* Wk   = (const float*)d_in[2];
  const float* Wv   = (const float*)d_in[3];
  const float* Wo   = (const float*)d_in[4];
  const float* bo   = (const float*)d_in[5];
  const float* ln1s = (const float*)d_in[6];
  const float* ln1b = (const float*)d_in[7];
  const float* ln2s = (const float*)d_in[8];
  const float* ln2b = (const float*)d_in[9];
  const float* W1   = (const float*)d_in[10];
  const float* b1   = (const float*)d_in[11];
  const float* W2   = (const float*)d_in[12];
  const float* b2   = (const float*)d_in[13];
  float* out = (float*)d_out;

  const int Mtok = 4096, D = 2048, DFF = 8192, NQKV = 6144;

  char* w = (char*)d_ws;
  u16* Wt_qkv = (u16*)w;  w += (size_t)NQKV * D * 2;
  u16* Wt_o   = (u16*)w;  w += (size_t)D * D * 2;
  u16* Wt_1   = (u16*)w;  w += (size_t)DFF * D * 2;
  u16* Wt_2   = (u16*)w;  w += (size_t)D * DFF * 2;
  u16* Xln    = (u16*)w;  w += (size_t)Mtok * D * 2;
  u16* QKV    = (u16*)w;  w += (size_t)Mtok * NQKV * 2;
  u16* CTX    = (u16*)w;  w += (size_t)Mtok * D * 2;
  u16* Y1     = QKV;      // aliases QKV+CTX after both are dead
  float* Hbuf = (float*)w; w += (size_t)Mtok * D * 4;

  const dim3 tb(32, 8, 1);
  transpose_cast<<<dim3(D / 32, D / 32), tb, 0, stream>>>(Wq, Wt_qkv,                    D, D);
  transpose_cast<<<dim3(D / 32, D / 32), tb, 0, stream>>>(Wk, Wt_qkv + (size_t)D * D,    D, D);
  transpose_cast<<<dim3(D / 32, D / 32), tb, 0, stream>>>(Wv, Wt_qkv + (size_t)2 * D * D,D, D);
  transpose_cast<<<dim3(D / 32, D / 32), tb, 0, stream>>>(Wo, Wt_o,                      D, D);
  transpose_cast<<<dim3(DFF / 32, D / 32), tb, 0, stream>>>(W1, Wt_1,                    D, DFF);
  transpose_cast<<<dim3(D / 32, DFF / 32), tb, 0, stream>>>(W2, Wt_2,                    DFF, D);

  ln_kernel<<<Mtok, 256, 0, stream>>>(x, ln1s, ln1b, Xln);

  // QKV: M=4096 N=6144 K=2048, MHALF=1 -> 768 blocks (3/CU)
  gemm8<1, 1, 0, 0, 0><<<dim3(768), 512, 0, stream>>>(
      Xln, Wt_qkv, nullptr, nullptr, nullptr, QKV, Mtok, NQKV, D);

  attn_kernel<<<dim3(16, 16, 2), 256, 0, stream>>>(QKV, CTX);

  // Wo: M=4096 N=2048 K=2048, MHALF=1 -> 256 blocks
  gemm8<1, 0, 1, 1, 0><<<dim3(256), 512, 0, stream>>>(
      CTX, Wt_o, bo, x, Hbuf, nullptr, Mtok, D, D);

  ln_kernel<<<Mtok, 256, 0, stream>>>(Hbuf, ln2s, ln2b, Xln);

  // FFN1: M=4096 N=8192 K=2048, MHALF=2 -> 512 blocks (2/CU)
  gemm8<2, 1, 1, 0, 1><<<dim3(512), 512, 0, stream>>>(
      Xln, Wt_1, b1, nullptr, nullptr, Y1, Mtok, DFF, D);

  // FFN2: M=4096 N=2048 K=8192, MHALF=1 -> 256 blocks
  gemm8<1, 0, 1, 1, 0><<<dim3(256), 512, 0, stream>>>(
      Y1, Wt_2, b2, Hbuf, out, nullptr, Mtok, D, DFF);
}

// Round 4
// 643.888 us; speedup vs baseline: 1.5369x; 1.1090x over previous
//
#include <hip/hip_runtime.h>
#include <cmath>

// ---------------------------------------------------------------------------
// Transformer block, bf16 MFMA. B=2,S=2048,D=2048,H=16,HD=128,DFF=8192,M=4096.
// GEMMs: phase-interleaved schedule (T2 swizzle + T3/T4 counted vmcnt + T5
// setprio), 512 thr = 8 waves, BK=64.  Attention: flash, QBLK=64, KVBLK=64,
// double-buffered K/V staged via global_load_lds (V from a pre-transposed
// global VT), in-LDS P, deferred softmax sum reduce.
// ---------------------------------------------------------------------------

typedef unsigned short u16;
typedef unsigned int   u32;
typedef float  f32x4  __attribute__((ext_vector_type(4)));
typedef short  s16x8  __attribute__((ext_vector_type(8)));
typedef short  s16x4  __attribute__((ext_vector_type(4)));
typedef __bf16 bf16x8 __attribute__((ext_vector_type(8)));

#define DEV __device__ __forceinline__

DEV u16 f2bf(float f) {
  union { float f; u32 u; } v; v.f = f;
  u32 u = v.u;
  u += 0x7fffu + ((u >> 16) & 1u);   // round-to-nearest-even
  return (u16)(u >> 16);
}

DEV f32x4 mfma16(s16x8 a, s16x8 b, f32x4 c) {
  return __builtin_amdgcn_mfma_f32_16x16x32_bf16(
      __builtin_bit_cast(bf16x8, a), __builtin_bit_cast(bf16x8, b), c, 0, 0, 0);
}

DEV float gelu_f(float x) {
  const float c = 0.7978845608028654f;  // sqrt(2/pi)
  return 0.5f * x * (1.0f + tanhf(c * (x + 0.044715f * x * x * x)));
}

// async global->LDS, 16B per lane. Dest is wave-uniform base + lane*16.
DEV void gload16(const u16* g, u16* l) {
  __builtin_amdgcn_global_load_lds(
      (const __attribute__((address_space(1))) u32*)(const void*)g,
      (__attribute__((address_space(3))) u32*)(void*)l, 16, 0, 0);
}

// ---------------------------------------------------------------------------
// Weight transpose + fp32->bf16 cast.  W: K x N (row-major)  ->  Wt: N x K.
// ---------------------------------------------------------------------------
__global__ __launch_bounds__(256) void transpose_cast(
    const float* __restrict__ W, u16* __restrict__ Wt, int K, int N) {
  __shared__ float tile[32][33];
  const int n0 = blockIdx.x * 32, k0 = blockIdx.y * 32;
  const int tx = threadIdx.x, ty = threadIdx.y;
#pragma unroll
  for (int i = 0; i < 4; ++i)
    tile[ty + 8 * i][tx] = W[(size_t)(k0 + ty + 8 * i) * N + n0 + tx];
  __syncthreads();
#pragma unroll
  for (int i = 0; i < 4; ++i)
    Wt[(size_t)(n0 + ty + 8 * i) * K + k0 + tx] = f2bf(tile[tx][ty + 8 * i]);
}

// ---------------------------------------------------------------------------
// V transpose: QKV V-section (per b,h: [s][d]) -> VT[(b*16+h)][d][s], bf16.
// ---------------------------------------------------------------------------
__global__ __launch_bounds__(256) void transpose_v(
    const u16* __restrict__ QKV, u16* __restrict__ VT) {
  __shared__ u16 tile[32][33];
  const int s0 = blockIdx.x * 32;
  const int d0 = blockIdx.y * 32;
  const int bh = blockIdx.z;
  const int b = bh >> 4, h = bh & 15;
  const int tx = threadIdx.x, ty = threadIdx.y;
  const u16* src = QKV + (long)b * 2048 * 6144 + 4096 + h * 128;
#pragma unroll
  for (int i = 0; i < 4; ++i)
    tile[ty + 8 * i][tx] = src[(long)(s0 + ty + 8 * i) * 6144 + d0 + tx];
  __syncthreads();
  u16* dst = VT + (long)bh * 128 * 2048;
#pragma unroll
  for (int i = 0; i < 4; ++i)
    dst[(long)(d0 + ty + 8 * i) * 2048 + s0 + tx] = tile[tx][ty + 8 * i];
}

// ---------------------------------------------------------------------------
// Row LayerNorm over D=2048, fp32 in -> bf16 out. One block (256 thr) per row.
// ---------------------------------------------------------------------------
__global__ __launch_bounds__(256) void ln_kernel(
    const float* __restrict__ X, const float* __restrict__ sc,
    const float* __restrict__ sh, u16* __restrict__ Y) {
  const int row = blockIdx.x, t = threadIdx.x;
  const float* xr = X + (size_t)row * 2048;
  float4 v0 = ((const float4*)xr)[t];
  float4 v1 = ((const float4*)xr)[t + 256];
  float s  = v0.x + v0.y + v0.z + v0.w + v1.x + v1.y + v1.z + v1.w;
  float qs = v0.x*v0.x + v0.y*v0.y + v0.z*v0.z + v0.w*v0.w
           + v1.x*v1.x + v1.y*v1.y + v1.z*v1.z + v1.w*v1.w;
#pragma unroll
  for (int off = 1; off < 64; off <<= 1) {
    s  += __shfl_xor(s, off);
    qs += __shfl_xor(qs, off);
  }
  __shared__ float rs[4], rq[4];
  if ((t & 63) == 0) { rs[t >> 6] = s; rq[t >> 6] = qs; }
  __syncthreads();
  const float st = rs[0] + rs[1] + rs[2] + rs[3];
  const float qt = rq[0] + rq[1] + rq[2] + rq[3];
  const float mean = st * (1.0f / 2048.0f);
  const float var  = qt * (1.0f / 2048.0f) - mean * mean;
  const float rstd = rsqrtf(var + 1e-5f);

  u16* yr = Y + (size_t)row * 2048;
  const int c0 = t * 4, c1 = 1024 + t * 4;
  s16x4 o0, o1;
  o0[0] = (short)f2bf(sc[c0+0] * (v0.x - mean) * rstd + sh[c0+0]);
  o0[1] = (short)f2bf(sc[c0+1] * (v0.y - mean) * rstd + sh[c0+1]);
  o0[2] = (short)f2bf(sc[c0+2] * (v0.z - mean) * rstd + sh[c0+2]);
  o0[3] = (short)f2bf(sc[c0+3] * (v0.w - mean) * rstd + sh[c0+3]);
  o1[0] = (short)f2bf(sc[c1+0] * (v1.x - mean) * rstd + sh[c1+0]);
  o1[1] = (short)f2bf(sc[c1+1] * (v1.y - mean) * rstd + sh[c1+1]);
  o1[2] = (short)f2bf(sc[c1+2] * (v1.z - mean) * rstd + sh[c1+2]);
  o1[3] = (short)f2bf(sc[c1+3] * (v1.w - mean) * rstd + sh[c1+3]);
  *(s16x4*)(yr + c0) = o0;
  *(s16x4*)(yr + c1) = o1;
}

// ---------------------------------------------------------------------------
// Phase-interleaved GEMM: C(MxN) = A(MxK) @ Bt(NxK)^T, bf16 in, BK=64.
// (unchanged from R3 — verified)
// ---------------------------------------------------------------------------
template<int MHALF, int STORE_BF16, int BIAS, int RES, int GELU_ACT>
__global__ __launch_bounds__(512, 2) void gemm8(
    const u16* __restrict__ A, const u16* __restrict__ Bt,
    const float* __restrict__ bias, const float* __restrict__ res,
    float* __restrict__ Cf, u16* __restrict__ Cb,
    int M, int N, int K) {
  constexpr int NPH   = 2 * MHALF;
  constexpr int ABUFS = (MHALF == 2) ? 2 : 3;
  constexpr int ASZ   = 8192 * MHALF;
  constexpr int BOFF  = ABUFS * ASZ;
  __shared__ u16 lds[BOFF + 2 * 16384];

  const int t9 = threadIdx.x;
  const int l = t9 & 63, w = t9 >> 6;
  const int r16 = l & 15, quad = l >> 4;
  const int wm = w >> 2, wn = w & 3;

  const int nbx = N >> 8;
  const int nwg = gridDim.x;
  const int cpx = nwg >> 3;
  const int bid = blockIdx.x;
  const int swz = (bid & 7) * cpx + (bid >> 3);
  const long m0 = (long)(swz / nbx) * (128 * MHALF);
  const long n0 = (long)(swz % nbx) * 256;

  const int NT = K >> 6;
  const int srow = t9 >> 3;
  const int scol = (t9 & 7) ^ (srow & 7);

  const u16* Abase = A  + (m0 + srow) * (long)K + scol * 8;
  const u16* Bbase = Bt + (n0 + srow) * (long)K + scol * 8;
  const long rowK64  = 64 * (long)K;
  const long rowK128 = 128 * (long)K;

  #define STAGE_A(tile, h) { \
    u16* d = &lds[((tile) % ABUFS) * ASZ + (h) * 8192 + w * 512]; \
    const u16* s = Abase + (h) * rowK128 + (long)(tile) * 64; \
    gload16(s, d); gload16(s + rowK64, d + 4096); }
  #define STAGE_B(tile, h) { \
    u16* d = &lds[BOFF + ((tile) & 1) * 16384 + (h) * 8192 + w * 512]; \
    const u16* s = Bbase + (h) * rowK128 + (long)(tile) * 64; \
    gload16(s, d); gload16(s + rowK64, d + 4096); }

  f32x4 acc[4 * MHALF][4] = {};

  if (MHALF == 2) {
    STAGE_B(0, 0); STAGE_B(0, 1); STAGE_A(0, 0); STAGE_A(0, 1);
    STAGE_B(1, 0); STAGE_B(1, 1);
    asm volatile("s_waitcnt vmcnt(4)" ::: "memory");
  } else {
    STAGE_B(0, 0); STAGE_B(0, 1); STAGE_A(0, 0); STAGE_A(1, 0);
    STAGE_B(1, 0); STAGE_B(1, 1);
    asm volatile("s_waitcnt vmcnt(6)" ::: "memory");
  }
  __builtin_amdgcn_sched_barrier(0);
  __builtin_amdgcn_s_barrier();

  s16x8 bf_[4][2];
  for (int t = 0; t < NT; ++t) {
    const int ab = t % ABUFS;
    const u16* Abuf = &lds[ab * ASZ];
    const u16* Bbuf = &lds[BOFF + (t & 1) * 16384];
#pragma unroll
    for (int p = 0; p < NPH; ++p) {
      if (p == 0) {
#pragma unroll
        for (int ni = 0; ni < 4; ++ni) {
          const int brow = wn * 64 + ni * 16 + r16;
#pragma unroll
          for (int ks = 0; ks < 2; ++ks)
            bf_[ni][ks] = *(const s16x8*)&Bbuf[brow * 64 + ((ks * 4 + quad) ^ (brow & 7)) * 8];
        }
      }
      s16x8 af[2][2];
#pragma unroll
      for (int mi = 0; mi < 2; ++mi) {
        const int arow = (MHALF == 2 ? wm * 128 : wm * 64) + (2 * p + mi) * 16 + r16;
#pragma unroll
        for (int ks = 0; ks < 2; ++ks)
          af[mi][ks] = *(const s16x8*)&Abuf[arow * 64 + ((ks * 4 + quad) ^ (arow & 7)) * 8];
      }
      if (MHALF == 2) {
        if (p < 2)       { if (t + 1 < NT) STAGE_A(t + 1, p); }
        else             { if (t + 2 < NT) STAGE_B(t + 2, p - 2); }
      } else {
        if (p == 0)      { if (t + 2 < NT) STAGE_A(t + 2, 0); }
        else             { if (t + 2 < NT) { STAGE_B(t + 2, 0); STAGE_B(t + 2, 1); } }
      }
      __builtin_amdgcn_sched_barrier(0);
      __builtin_amdgcn_s_barrier();
      asm volatile("s_waitcnt lgkmcnt(0)" ::: "memory");
      __builtin_amdgcn_sched_barrier(0);
      __builtin_amdgcn_s_setprio(1);
#pragma unroll
      for (int mi = 0; mi < 2; ++mi)
#pragma unroll
        for (int ni = 0; ni < 4; ++ni)
#pragma unroll
          for (int ks = 0; ks < 2; ++ks)
            acc[2 * p + mi][ni] = mfma16(af[mi][ks], bf_[ni][ks], acc[2 * p + mi][ni]);
      __builtin_amdgcn_s_setprio(0);
      __builtin_amdgcn_sched_barrier(0);
      if (p == NPH - 1) {
        if (MHALF == 2) {
          if (t + 2 < NT) { asm volatile("s_waitcnt vmcnt(4)" ::: "memory"); }
          else            { asm volatile("s_waitcnt vmcnt(0)" ::: "memory"); }
        } else {
          if (t + 2 < NT) { asm volatile("s_waitcnt vmcnt(6)" ::: "memory"); }
          else            { asm volatile("s_waitcnt vmcnt(0)" ::: "memory"); }
        }
        __builtin_amdgcn_sched_barrier(0);
      }
      __builtin_amdgcn_s_barrier();
    }
  }
  #undef STAGE_A
  #undef STAGE_B

#pragma unroll
  for (int mi = 0; mi < 4 * MHALF; ++mi) {
#pragma unroll
    for (int ni = 0; ni < 4; ++ni) {
#pragma unroll
      for (int r = 0; r < 4; ++r) {
        const long gr = m0 + (MHALF == 2 ? wm * 128 : wm * 64) + mi * 16 + quad * 4 + r;
        const long gc = n0 + wn * 64 + ni * 16 + r16;
        float v = acc[mi][ni][r];
        if (BIAS)     v += bias[gc];
        if (GELU_ACT) v  = gelu_f(v);
        if (RES)      v += res[gr * N + gc];
        if (STORE_BF16) Cb[gr * N + gc] = f2bf(v);
        else            Cf[gr * N + gc] = v;
      }
    }
  }
}

// ---------------------------------------------------------------------------
// Causal flash attention, 4 waves/block, QBLK=64 (16 q-rows/wave), KVBLK=64.
// K and V^T staged via global_load_lds (pre-swizzled source), double-buffered
// (stage t+1 issued before compute of t; vmcnt(0)+barrier at tile end).
// Softmax: per-tile max reduce only; sum reduced once per q-tile; rescale
// skipped when alpha==1; mask applied on diagonal tiles only; waves skip
// fully-masked tiles. Blocks process q-tile pair {p, 31-p} (uniform 34 tiles).
// ---------------------------------------------------------------------------
__global__ __launch_bounds__(256) void attn_kernel(
    const u16* __restrict__ QKV, const u16* __restrict__ VT,
    u16* __restrict__ CTX) {
  __shared__ u16 Ks[2][64 * 128];   // [kv][d], swizzled 16B slots
  __shared__ u16 Vs[2][128 * 64];   // [d][kv], swizzled 16B slots
  __shared__ u16 Pl[4][16 * 64];    // per-wave P

  const int t = threadIdx.x;
  const int lane = t & 63, w = t >> 6;
  const int r16 = lane & 15, quad = lane >> 4;
  const int h = blockIdx.y, b = blockIdx.z;
  const long LDQ = 6144;
  const u16* Qb = QKV + (long)b * 2048 * LDQ + h * 128;
  const u16* Kb = Qb + 2048;
  const u16* Vtb = VT + (long)(b * 16 + h) * 128 * 2048;
  u16* Pw = Pl[w];
  const float scale = 0.08838834764831845f;  // 1/sqrt(128)

  const int k_row = t >> 4;   // +i*16
  const int k_slot = t & 15;
  const int v_row = t >> 3;   // +i*32
  const int v_slot = t & 7;

#define STAGE_KV(kt_, buf_)                                                    \
  {                                                                            \
    const int kb_ = (kt_) * 64;                                                \
    _Pragma("unroll") for (int i = 0; i < 4; ++i) {                            \
      const int row = i * 16 + k_row;                                          \
      gload16(Kb + (long)(kb_ + row) * LDQ + (k_slot ^ (row & 7)) * 8,         \
              &Ks[buf_][i * 2048 + w * 512]);                                  \
    }                                                                          \
    _Pragma("unroll") for (int i = 0; i < 4; ++i) {                            \
      const int d_ = i * 32 + v_row;                                           \
      gload16(Vtb + (long)d_ * 2048 + kb_ + (v_slot ^ (d_ & 7)) * 8,           \
              &Vs[buf_][i * 2048 + w * 512]);                                  \
    }                                                                          \
  }

  for (int half = 0; half < 2; ++half) {
    const int qt = half ? (31 - (int)blockIdx.x) : (int)blockIdx.x;
    const int qw = qt * 64 + w * 16;

    s16x8 aq[4];
#pragma unroll
    for (int ks = 0; ks < 4; ++ks)
      aq[ks] = *(const s16x8*)(Qb + (long)(qw + r16) * LDQ + ks * 32 + quad * 8);

    f32x4 o[8] = {};
    float mrun[4], lrun[4];
#pragma unroll
    for (int r = 0; r < 4; ++r) { mrun[r] = -1e30f; lrun[r] = 0.0f; }

    __builtin_amdgcn_s_barrier();   // prior reads of buf0 done
    STAGE_KV(0, 0);
    asm volatile("s_waitcnt vmcnt(0)" ::: "memory");
    __builtin_amdgcn_s_barrier();

    for (int kt = 0; kt <= qt; ++kt) {
      const int kbase = kt * 64;
      const int cur = kt & 1;
      if (kt < qt) STAGE_KV(kt + 1, cur ^ 1);   // into dead buffer (WAR ok)

      if (kbase <= qw + 15) {   // wave has >=1 unmasked row in this tile
        // --- QK^T ---
        f32x4 sc[4];
#pragma unroll
        for (int kh = 0; kh < 4; ++kh) {
          f32x4 z = {};
          sc[kh] = z;
          const int krow = kh * 16 + r16;
#pragma unroll
          for (int ks = 0; ks < 4; ++ks) {
            const s16x8 bk =
                *(const s16x8*)&Ks[cur][krow * 128 + ((ks * 4 + quad) ^ (krow & 7)) * 8];
            sc[kh] = mfma16(aq[ks], bk, sc[kh]);
          }
        }
        // --- online softmax ---
        const bool need_mask = (kbase + 63 > qw);
        float alpha[4];
#pragma unroll
        for (int r = 0; r < 4; ++r) {
          const int q = qw + quad * 4 + r;
          float sv[4];
#pragma unroll
          for (int kh = 0; kh < 4; ++kh) {
            float s = sc[kh][r] * scale;
            if (need_mask && (kbase + kh * 16 + r16 > q)) s = -1e30f;
            sv[kh] = s;
          }
          float mx = fmaxf(fmaxf(sv[0], sv[1]), fmaxf(sv[2], sv[3]));
#pragma unroll
          for (int off = 1; off < 16; off <<= 1) mx = fmaxf(mx, __shfl_xor(mx, off));
          const float mn = fmaxf(mrun[r], mx);
          alpha[r] = __expf(mrun[r] - mn);
          mrun[r] = mn;
          const int prow = quad * 4 + r;
          float ps = 0.0f;
#pragma unroll
          for (int kh = 0; kh < 4; ++kh) {
            const float p = __expf(sv[kh] - mn);
            ps += p;
            Pw[(prow * 64 + kh * 16 + r16) ^ ((prow & 7) << 3)] = f2bf(p);
          }
          lrun[r] = lrun[r] * alpha[r] + ps;   // per-lane partial sum
        }
        if (alpha[0] != 1.0f || alpha[1] != 1.0f || alpha[2] != 1.0f || alpha[3] != 1.0f) {
#pragma unroll
          for (int ds = 0; ds < 8; ++ds)
#pragma unroll
            for (int r = 0; r < 4; ++r) o[ds][r] *= alpha[r];
        }
        // --- PV ---
#pragma unroll
        for (int s = 0; s < 2; ++s) {
          const s16x8 ap =
              *(const s16x8*)&Pw[(r16 * 64 + s * 32 + quad * 8) ^ ((r16 & 7) << 3)];
#pragma unroll
          for (int ds = 0; ds < 8; ++ds) {
            const int d = ds * 16 + r16;
            const s16x8 bv =
                *(const s16x8*)&Vs[cur][d * 64 + ((s * 4 + quad) ^ (d & 7)) * 8];
            o[ds] = mfma16(ap, bv, o[ds]);
          }
        }
      }

      asm volatile("s_waitcnt vmcnt(0)" ::: "memory");  // t+1 staged long ago
      __builtin_amdgcn_s_barrier();
    }

    // --- final sum reduce + epilogue ---
#pragma unroll
    for (int r = 0; r < 4; ++r)
#pragma unroll
      for (int off = 1; off < 16; off <<= 1) lrun[r] += __shfl_xor(lrun[r], off);

#pragma unroll
    for (int ds = 0; ds < 8; ++ds)
#pragma unroll
      for (int r = 0; r < 4; ++r) {
        const float v = o[ds][r] / lrun[r];
        CTX[(long)(b * 2048 + qw + quad * 4 + r) * 2048 + h * 128 + ds * 16 + r16] = f2bf(v);
      }
  }
#undef STAGE_KV
}

// ---------------------------------------------------------------------------
extern "C" void kernel_launch(void* const* d_in, const int* in_sizes, int n_in,
                              void* d_out, int out_size, void* d_ws, size_t ws_size,
                              hipStream_t stream) {
  (void)in_sizes; (void)n_in; (void)out_size; (void)ws_size;
  const float* x    = (const float*)d_in[0];
  const float* Wq   = (const float*)d_in[1];
  const float* Wk   = (const float*)d_in[2];
  const float* Wv   = (const float*)d_in[3];
  const float* Wo   = (const float*)d_in[4];
  const float* bo   = (const float*)d_in[5];
  const float* ln1s = (const float*)d_in[6];
  const float* ln1b = (const float*)d_in[7];
  const float* ln2s = (const float*)d_in[8];
  const float* ln2b = (const float*)d_in[9];
  const float* W1   = (const float*)d_in[10];
  const float* b1   = (const float*)d_in[11];
  const float* W2   = (const float*)d_in[12];
  const float* b2   = (const float*)d_in[13];
  float* out = (float*)d_out;

  const int Mtok = 4096, D = 2048, DFF = 8192, NQKV = 6144;

  char* w = (char*)d_ws;
  u16* Wt_qkv = (u16*)w;  w += (size_t)NQKV * D * 2;
  u16* Wt_o   = (u16*)w;  w += (size_t)D * D * 2;
  u16* Wt_1   = (u16*)w;  w += (size_t)DFF * D * 2;
  u16* Wt_2   = (u16*)w;  w += (size_t)D * DFF * 2;
  u16* Xln    = (u16*)w;  w += (size_t)Mtok * D * 2;
  u16* QKV    = (u16*)w;  w += (size_t)Mtok * NQKV * 2;
  u16* CTX    = (u16*)w;  w += (size_t)Mtok * D * 2;
  u16* Y1     = QKV;        // aliases QKV+CTX after both are dead
  u16* VTb    = Wt_qkv;     // VT (16.8MB) aliases Wt_qkv (25.2MB, dead post-QKV)
  float* Hbuf = (float*)w; w += (size_t)Mtok * D * 4;

  const dim3 tb(32, 8, 1);
  transpose_cast<<<dim3(D / 32, D / 32), tb, 0, stream>>>(Wq, Wt_qkv,                    D, D);
  transpose_cast<<<dim3(D / 32, D / 32), tb, 0, stream>>>(Wk, Wt_qkv + (size_t)D * D,    D, D);
  transpose_cast<<<dim3(D / 32, D / 32), tb, 0, stream>>>(Wv, Wt_qkv + (size_t)2 * D * D,D, D);
  transpose_cast<<<dim3(D / 32, D / 32), tb, 0, stream>>>(Wo, Wt_o,                      D, D);
  transpose_cast<<<dim3(DFF / 32, D / 32), tb, 0, stream>>>(W1, Wt_1,                    D, DFF);
  transpose_cast<<<dim3(D / 32, DFF / 32), tb, 0, stream>>>(W2, Wt_2,                    DFF, D);

  ln_kernel<<<Mtok, 256, 0, stream>>>(x, ln1s, ln1b, Xln);

  // QKV: M=4096 N=6144 K=2048, MHALF=1 -> 768 blocks (3 rounds of 256 CUs)
  gemm8<1, 1, 0, 0, 0><<<dim3(768), 512, 0, stream>>>(
      Xln, Wt_qkv, nullptr, nullptr, nullptr, QKV, Mtok, NQKV, D);

  // V -> VT (aliases Wt_qkv, dead after the QKV GEMM)
  transpose_v<<<dim3(64, 4, 32), tb, 0, stream>>>(QKV, VTb);

  attn_kernel<<<dim3(16, 16, 2), 256, 0, stream>>>(QKV, VTb, CTX);

  // Wo: M=4096 N=2048 K=2048, MHALF=1 -> 256 blocks
  gemm8<1, 0, 1, 1, 0><<<dim3(256), 512, 0, stream>>>(
      CTX, Wt_o, bo, x, Hbuf, nullptr, Mtok, D, D);

  ln_kernel<<<Mtok, 256, 0, stream>>>(Hbuf, ln2s, ln2b, Xln);

  // FFN1: M=4096 N=8192 K=2048, MHALF=2 -> 512 blocks
  gemm8<2, 1, 1, 0, 1><<<dim3(512), 512, 0, stream>>>(
      Xln, Wt_1, b1, nullptr, nullptr, Y1, Mtok, DFF, D);

  // FFN2: M=4096 N=2048 K=8192, MHALF=1 -> 256 blocks
  gemm8<1, 0, 1, 1, 0><<<dim3(256), 512, 0, stream>>>(
      Y1, Wt_2, b2, Hbuf, out, nullptr, Mtok, D, DFF);
}

// Round 5
// 624.868 us; speedup vs baseline: 1.5836x; 1.0304x over previous
//
#include <hip/hip_runtime.h>
#include <cmath>

// ---------------------------------------------------------------------------
// Transformer block, bf16 MFMA. B=2,S=2048,D=2048,H=16,HD=128,DFF=8192,M=4096.
// GEMMs: phase-interleaved schedule (T2 swizzle + T3/T4 counted vmcnt + T5
// setprio), 512 thr = 8 waves, BK=64, 2-D XCD region rasterization for L2
// panel reuse.  Attention: flash, double-buffered K/V via global_load_lds.
// ---------------------------------------------------------------------------

typedef unsigned short u16;
typedef unsigned int   u32;
typedef float  f32x4  __attribute__((ext_vector_type(4)));
typedef short  s16x8  __attribute__((ext_vector_type(8)));
typedef short  s16x4  __attribute__((ext_vector_type(4)));
typedef __bf16 bf16x8 __attribute__((ext_vector_type(8)));

#define DEV __device__ __forceinline__

DEV u16 f2bf(float f) {
  union { float f; u32 u; } v; v.f = f;
  u32 u = v.u;
  u += 0x7fffu + ((u >> 16) & 1u);   // round-to-nearest-even
  return (u16)(u >> 16);
}

DEV f32x4 mfma16(s16x8 a, s16x8 b, f32x4 c) {
  return __builtin_amdgcn_mfma_f32_16x16x32_bf16(
      __builtin_bit_cast(bf16x8, a), __builtin_bit_cast(bf16x8, b), c, 0, 0, 0);
}

DEV float gelu_f(float x) {
  // tanh-gelu with exp-based tanh (hw v_exp_f32; avoids slow libm tanhf)
  const float c = 0.7978845608028654f;  // sqrt(2/pi)
  const float z = c * (x + 0.044715f * x * x * x);
  const float e = __expf(2.0f * z);          // inf for large z -> th=1; 0 -> th=-1
  const float th = 1.0f - 2.0f / (e + 1.0f);
  return 0.5f * x * (1.0f + th);
}

// async global->LDS, 16B per lane. Dest is wave-uniform base + lane*16.
DEV void gload16(const u16* g, u16* l) {
  __builtin_amdgcn_global_load_lds(
      (const __attribute__((address_space(1))) u32*)(const void*)g,
      (__attribute__((address_space(3))) u32*)(void*)l, 16, 0, 0);
}

// ---------------------------------------------------------------------------
// Weight transpose + fp32->bf16 cast.  W: K x N (row-major)  ->  Wt: N x K.
// ---------------------------------------------------------------------------
__global__ __launch_bounds__(256) void transpose_cast(
    const float* __restrict__ W, u16* __restrict__ Wt, int K, int N) {
  __shared__ float tile[32][33];
  const int n0 = blockIdx.x * 32, k0 = blockIdx.y * 32;
  const int tx = threadIdx.x, ty = threadIdx.y;
#pragma unroll
  for (int i = 0; i < 4; ++i)
    tile[ty + 8 * i][tx] = W[(size_t)(k0 + ty + 8 * i) * N + n0 + tx];
  __syncthreads();
#pragma unroll
  for (int i = 0; i < 4; ++i)
    Wt[(size_t)(n0 + ty + 8 * i) * K + k0 + tx] = f2bf(tile[tx][ty + 8 * i]);
}

// ---------------------------------------------------------------------------
// V transpose: QKV V-section (per b,h: [s][d]) -> VT[(b*16+h)][d][s], bf16.
// ---------------------------------------------------------------------------
__global__ __launch_bounds__(256) void transpose_v(
    const u16* __restrict__ QKV, u16* __restrict__ VT) {
  __shared__ u16 tile[32][33];
  const int s0 = blockIdx.x * 32;
  const int d0 = blockIdx.y * 32;
  const int bh = blockIdx.z;
  const int b = bh >> 4, h = bh & 15;
  const int tx = threadIdx.x, ty = threadIdx.y;
  const u16* src = QKV + (long)b * 2048 * 6144 + 4096 + h * 128;
#pragma unroll
  for (int i = 0; i < 4; ++i)
    tile[ty + 8 * i][tx] = src[(long)(s0 + ty + 8 * i) * 6144 + d0 + tx];
  __syncthreads();
  u16* dst = VT + (long)bh * 128 * 2048;
#pragma unroll
  for (int i = 0; i < 4; ++i)
    dst[(long)(d0 + ty + 8 * i) * 2048 + s0 + tx] = tile[tx][ty + 8 * i];
}

// ---------------------------------------------------------------------------
// Row LayerNorm over D=2048, fp32 in -> bf16 out. One block (256 thr) per row.
// ---------------------------------------------------------------------------
__global__ __launch_bounds__(256) void ln_kernel(
    const float* __restrict__ X, const float* __restrict__ sc,
    const float* __restrict__ sh, u16* __restrict__ Y) {
  const int row = blockIdx.x, t = threadIdx.x;
  const float* xr = X + (size_t)row * 2048;
  float4 v0 = ((const float4*)xr)[t];
  float4 v1 = ((const float4*)xr)[t + 256];
  float s  = v0.x + v0.y + v0.z + v0.w + v1.x + v1.y + v1.z + v1.w;
  float qs = v0.x*v0.x + v0.y*v0.y + v0.z*v0.z + v0.w*v0.w
           + v1.x*v1.x + v1.y*v1.y + v1.z*v1.z + v1.w*v1.w;
#pragma unroll
  for (int off = 1; off < 64; off <<= 1) {
    s  += __shfl_xor(s, off);
    qs += __shfl_xor(qs, off);
  }
  __shared__ float rs[4], rq[4];
  if ((t & 63) == 0) { rs[t >> 6] = s; rq[t >> 6] = qs; }
  __syncthreads();
  const float st = rs[0] + rs[1] + rs[2] + rs[3];
  const float qt = rq[0] + rq[1] + rq[2] + rq[3];
  const float mean = st * (1.0f / 2048.0f);
  const float var  = qt * (1.0f / 2048.0f) - mean * mean;
  const float rstd = rsqrtf(var + 1e-5f);

  u16* yr = Y + (size_t)row * 2048;
  const int c0 = t * 4, c1 = 1024 + t * 4;
  s16x4 o0, o1;
  o0[0] = (short)f2bf(sc[c0+0] * (v0.x - mean) * rstd + sh[c0+0]);
  o0[1] = (short)f2bf(sc[c0+1] * (v0.y - mean) * rstd + sh[c0+1]);
  o0[2] = (short)f2bf(sc[c0+2] * (v0.z - mean) * rstd + sh[c0+2]);
  o0[3] = (short)f2bf(sc[c0+3] * (v0.w - mean) * rstd + sh[c0+3]);
  o1[0] = (short)f2bf(sc[c1+0] * (v1.x - mean) * rstd + sh[c1+0]);
  o1[1] = (short)f2bf(sc[c1+1] * (v1.y - mean) * rstd + sh[c1+1]);
  o1[2] = (short)f2bf(sc[c1+2] * (v1.z - mean) * rstd + sh[c1+2]);
  o1[3] = (short)f2bf(sc[c1+3] * (v1.w - mean) * rstd + sh[c1+3]);
  *(s16x4*)(yr + c0) = o0;
  *(s16x4*)(yr + c1) = o1;
}

// ---------------------------------------------------------------------------
// Phase-interleaved GEMM: C(MxN) = A(MxK) @ Bt(NxK)^T, bf16 in, BK=64.
// 2-D XCD region rasterization: xcd = bid&7 owns an rr x rc tile region
// (regions tile the (nbm x nbx) grid: (nbm/rr)*(nbx/rc) == 8), col-major
// within region so co-resident blocks share A-rows and B-cols in L2.
// ---------------------------------------------------------------------------
template<int MHALF, int STORE_BF16, int BIAS, int RES, int GELU_ACT>
__global__ __launch_bounds__(512, 2) void gemm8(
    const u16* __restrict__ A, const u16* __restrict__ Bt,
    const float* __restrict__ bias, const float* __restrict__ res,
    float* __restrict__ Cf, u16* __restrict__ Cb,
    int M, int N, int K, int rr, int rc) {
  constexpr int NPH   = 2 * MHALF;
  constexpr int ABUFS = (MHALF == 2) ? 2 : 3;
  constexpr int ASZ   = 8192 * MHALF;
  constexpr int BOFF  = ABUFS * ASZ;
  __shared__ u16 lds[BOFF + 2 * 16384];

  const int t9 = threadIdx.x;
  const int l = t9 & 63, w = t9 >> 6;
  const int r16 = l & 15, quad = l >> 4;
  const int wm = w >> 2, wn = w & 3;

  // 2-D region rasterization
  const int nbx = N >> 8;
  const int bid = blockIdx.x;
  const int xcd = bid & 7, j = bid >> 3;
  const int nregc = nbx / rc;
  const int m_t = (xcd / nregc) * rr + (j % rr);
  const int n_t = (xcd % nregc) * rc + (j / rr);
  const long m0 = (long)m_t * (128 * MHALF);
  const long n0 = (long)n_t * 256;

  const int NT = K >> 6;
  const int srow = t9 >> 3;
  const int scol = (t9 & 7) ^ (srow & 7);

  const u16* Abase = A  + (m0 + srow) * (long)K + scol * 8;
  const u16* Bbase = Bt + (n0 + srow) * (long)K + scol * 8;
  const long rowK64  = 64 * (long)K;
  const long rowK128 = 128 * (long)K;

  #define STAGE_A(tile, h) { \
    u16* d = &lds[((tile) % ABUFS) * ASZ + (h) * 8192 + w * 512]; \
    const u16* s = Abase + (h) * rowK128 + (long)(tile) * 64; \
    gload16(s, d); gload16(s + rowK64, d + 4096); }
  #define STAGE_B(tile, h) { \
    u16* d = &lds[BOFF + ((tile) & 1) * 16384 + (h) * 8192 + w * 512]; \
    const u16* s = Bbase + (h) * rowK128 + (long)(tile) * 64; \
    gload16(s, d); gload16(s + rowK64, d + 4096); }

  f32x4 acc[4 * MHALF][4] = {};

  if (MHALF == 2) {
    STAGE_B(0, 0); STAGE_B(0, 1); STAGE_A(0, 0); STAGE_A(0, 1);
    STAGE_B(1, 0); STAGE_B(1, 1);
    asm volatile("s_waitcnt vmcnt(4)" ::: "memory");
  } else {
    STAGE_B(0, 0); STAGE_B(0, 1); STAGE_A(0, 0); STAGE_A(1, 0);
    STAGE_B(1, 0); STAGE_B(1, 1);
    asm volatile("s_waitcnt vmcnt(6)" ::: "memory");
  }
  __builtin_amdgcn_sched_barrier(0);
  __builtin_amdgcn_s_barrier();

  s16x8 bf_[4][2];
  for (int t = 0; t < NT; ++t) {
    const int ab = t % ABUFS;
    const u16* Abuf = &lds[ab * ASZ];
    const u16* Bbuf = &lds[BOFF + (t & 1) * 16384];
#pragma unroll
    for (int p = 0; p < NPH; ++p) {
      if (p == 0) {
#pragma unroll
        for (int ni = 0; ni < 4; ++ni) {
          const int brow = wn * 64 + ni * 16 + r16;
#pragma unroll
          for (int ks = 0; ks < 2; ++ks)
            bf_[ni][ks] = *(const s16x8*)&Bbuf[brow * 64 + ((ks * 4 + quad) ^ (brow & 7)) * 8];
        }
      }
      s16x8 af[2][2];
#pragma unroll
      for (int mi = 0; mi < 2; ++mi) {
        const int arow = (MHALF == 2 ? wm * 128 : wm * 64) + (2 * p + mi) * 16 + r16;
#pragma unroll
        for (int ks = 0; ks < 2; ++ks)
          af[mi][ks] = *(const s16x8*)&Abuf[arow * 64 + ((ks * 4 + quad) ^ (arow & 7)) * 8];
      }
      if (MHALF == 2) {
        if (p < 2)       { if (t + 1 < NT) STAGE_A(t + 1, p); }
        else             { if (t + 2 < NT) STAGE_B(t + 2, p - 2); }
      } else {
        if (p == 0)      { if (t + 2 < NT) STAGE_A(t + 2, 0); }
        else             { if (t + 2 < NT) { STAGE_B(t + 2, 0); STAGE_B(t + 2, 1); } }
      }
      __builtin_amdgcn_sched_barrier(0);
      __builtin_amdgcn_s_barrier();
      asm volatile("s_waitcnt lgkmcnt(0)" ::: "memory");
      __builtin_amdgcn_sched_barrier(0);
      __builtin_amdgcn_s_setprio(1);
#pragma unroll
      for (int mi = 0; mi < 2; ++mi)
#pragma unroll
        for (int ni = 0; ni < 4; ++ni)
#pragma unroll
          for (int ks = 0; ks < 2; ++ks)
            acc[2 * p + mi][ni] = mfma16(af[mi][ks], bf_[ni][ks], acc[2 * p + mi][ni]);
      __builtin_amdgcn_s_setprio(0);
      __builtin_amdgcn_sched_barrier(0);
      if (p == NPH - 1) {
        if (MHALF == 2) {
          if (t + 2 < NT) { asm volatile("s_waitcnt vmcnt(4)" ::: "memory"); }
          else            { asm volatile("s_waitcnt vmcnt(0)" ::: "memory"); }
        } else {
          if (t + 2 < NT) { asm volatile("s_waitcnt vmcnt(6)" ::: "memory"); }
          else            { asm volatile("s_waitcnt vmcnt(0)" ::: "memory"); }
        }
        __builtin_amdgcn_sched_barrier(0);
      }
      __builtin_amdgcn_s_barrier();
    }
  }
  #undef STAGE_A
  #undef STAGE_B

#pragma unroll
  for (int mi = 0; mi < 4 * MHALF; ++mi) {
#pragma unroll
    for (int ni = 0; ni < 4; ++ni) {
#pragma unroll
      for (int r = 0; r < 4; ++r) {
        const long gr = m0 + (MHALF == 2 ? wm * 128 : wm * 64) + mi * 16 + quad * 4 + r;
        const long gc = n0 + wn * 64 + ni * 16 + r16;
        float v = acc[mi][ni][r];
        if (BIAS)     v += bias[gc];
        if (GELU_ACT) v  = gelu_f(v);
        if (RES)      v += res[gr * N + gc];
        if (STORE_BF16) Cb[gr * N + gc] = f2bf(v);
        else            Cf[gr * N + gc] = v;
      }
    }
  }
}

// ---------------------------------------------------------------------------
// Causal flash attention, 4 waves/block, QBLK=64 (16 q-rows/wave), KVBLK=64.
// Double-buffered K/V^T staged via global_load_lds (pre-swizzled source).
// ---------------------------------------------------------------------------
__global__ __launch_bounds__(256) void attn_kernel(
    const u16* __restrict__ QKV, const u16* __restrict__ VT,
    u16* __restrict__ CTX) {
  __shared__ u16 Ks[2][64 * 128];   // [kv][d], swizzled 16B slots
  __shared__ u16 Vs[2][128 * 64];   // [d][kv], swizzled 16B slots
  __shared__ u16 Pl[4][16 * 64];    // per-wave P

  const int t = threadIdx.x;
  const int lane = t & 63, w = t >> 6;
  const int r16 = lane & 15, quad = lane >> 4;
  const int h = blockIdx.y, b = blockIdx.z;
  const long LDQ = 6144;
  const u16* Qb = QKV + (long)b * 2048 * LDQ + h * 128;
  const u16* Kb = Qb + 2048;
  const u16* Vtb = VT + (long)(b * 16 + h) * 128 * 2048;
  u16* Pw = Pl[w];
  const float scale = 0.08838834764831845f;  // 1/sqrt(128)

  const int k_row = t >> 4;   // +i*16
  const int k_slot = t & 15;
  const int v_row = t >> 3;   // +i*32
  const int v_slot = t & 7;

#define STAGE_KV(kt_, buf_)                                                    \
  {                                                                            \
    const int kb_ = (kt_) * 64;                                                \
    _Pragma("unroll") for (int i = 0; i < 4; ++i) {                            \
      const int row = i * 16 + k_row;                                          \
      gload16(Kb + (long)(kb_ + row) * LDQ + (k_slot ^ (row & 7)) * 8,         \
              &Ks[buf_][i * 2048 + w * 512]);                                  \
    }                                                                          \
    _Pragma("unroll") for (int i = 0; i < 4; ++i) {                            \
      const int d_ = i * 32 + v_row;                                           \
      gload16(Vtb + (long)d_ * 2048 + kb_ + (v_slot ^ (d_ & 7)) * 8,           \
              &Vs[buf_][i * 2048 + w * 512]);                                  \
    }                                                                          \
  }

  for (int half = 0; half < 2; ++half) {
    const int qt = half ? (31 - (int)blockIdx.x) : (int)blockIdx.x;
    const int qw = qt * 64 + w * 16;

    s16x8 aq[4];
#pragma unroll
    for (int ks = 0; ks < 4; ++ks)
      aq[ks] = *(const s16x8*)(Qb + (long)(qw + r16) * LDQ + ks * 32 + quad * 8);

    f32x4 o[8] = {};
    float mrun[4], lrun[4];
#pragma unroll
    for (int r = 0; r < 4; ++r) { mrun[r] = -1e30f; lrun[r] = 0.0f; }

    __builtin_amdgcn_s_barrier();   // prior reads of buf0 done
    STAGE_KV(0, 0);
    asm volatile("s_waitcnt vmcnt(0)" ::: "memory");
    __builtin_amdgcn_s_barrier();

    for (int kt = 0; kt <= qt; ++kt) {
      const int kbase = kt * 64;
      const int cur = kt & 1;
      if (kt < qt) STAGE_KV(kt + 1, cur ^ 1);   // into dead buffer (WAR ok)

      if (kbase <= qw + 15) {   // wave has >=1 unmasked row in this tile
        // --- QK^T ---
        f32x4 sc[4];
#pragma unroll
        for (int kh = 0; kh < 4; ++kh) {
          f32x4 z = {};
          sc[kh] = z;
          const int krow = kh * 16 + r16;
#pragma unroll
          for (int ks = 0; ks < 4; ++ks) {
            const s16x8 bk =
                *(const s16x8*)&Ks[cur][krow * 128 + ((ks * 4 + quad) ^ (krow & 7)) * 8];
            sc[kh] = mfma16(aq[ks], bk, sc[kh]);
          }
        }
        // --- online softmax ---
        const bool need_mask = (kbase + 63 > qw);
        float alpha[4];
#pragma unroll
        for (int r = 0; r < 4; ++r) {
          const int q = qw + quad * 4 + r;
          float sv[4];
#pragma unroll
          for (int kh = 0; kh < 4; ++kh) {
            float s = sc[kh][r] * scale;
            if (need_mask && (kbase + kh * 16 + r16 > q)) s = -1e30f;
            sv[kh] = s;
          }
          float mx = fmaxf(fmaxf(sv[0], sv[1]), fmaxf(sv[2], sv[3]));
#pragma unroll
          for (int off = 1; off < 16; off <<= 1) mx = fmaxf(mx, __shfl_xor(mx, off));
          const float mn = fmaxf(mrun[r], mx);
          alpha[r] = __expf(mrun[r] - mn);
          mrun[r] = mn;
          const int prow = quad * 4 + r;
          float ps = 0.0f;
#pragma unroll
          for (int kh = 0; kh < 4; ++kh) {
            const float p = __expf(sv[kh] - mn);
            ps += p;
            Pw[(prow * 64 + kh * 16 + r16) ^ ((prow & 7) << 3)] = f2bf(p);
          }
          lrun[r] = lrun[r] * alpha[r] + ps;   // per-lane partial sum
        }
        if (alpha[0] != 1.0f || alpha[1] != 1.0f || alpha[2] != 1.0f || alpha[3] != 1.0f) {
#pragma unroll
          for (int ds = 0; ds < 8; ++ds)
#pragma unroll
            for (int r = 0; r < 4; ++r) o[ds][r] *= alpha[r];
        }
        // --- PV ---
#pragma unroll
        for (int s = 0; s < 2; ++s) {
          const s16x8 ap =
              *(const s16x8*)&Pw[(r16 * 64 + s * 32 + quad * 8) ^ ((r16 & 7) << 3)];
#pragma unroll
          for (int ds = 0; ds < 8; ++ds) {
            const int d = ds * 16 + r16;
            const s16x8 bv =
                *(const s16x8*)&Vs[cur][d * 64 + ((s * 4 + quad) ^ (d & 7)) * 8];
            o[ds] = mfma16(ap, bv, o[ds]);
          }
        }
      }

      asm volatile("s_waitcnt vmcnt(0)" ::: "memory");  // t+1 staged long ago
      __builtin_amdgcn_s_barrier();
    }

    // --- final sum reduce + epilogue ---
#pragma unroll
    for (int r = 0; r < 4; ++r)
#pragma unroll
      for (int off = 1; off < 16; off <<= 1) lrun[r] += __shfl_xor(lrun[r], off);

#pragma unroll
    for (int ds = 0; ds < 8; ++ds)
#pragma unroll
      for (int r = 0; r < 4; ++r) {
        const float v = o[ds][r] / lrun[r];
        CTX[(long)(b * 2048 + qw + quad * 4 + r) * 2048 + h * 128 + ds * 16 + r16] = f2bf(v);
      }
  }
#undef STAGE_KV
}

// ---------------------------------------------------------------------------
extern "C" void kernel_launch(void* const* d_in, const int* in_sizes, int n_in,
                              void* d_out, int out_size, void* d_ws, size_t ws_size,
                              hipStream_t stream) {
  (void)in_sizes; (void)n_in; (void)out_size; (void)ws_size;
  const float* x    = (const float*)d_in[0];
  const float* Wq   = (const float*)d_in[1];
  const float* Wk   = (const float*)d_in[2];
  const float* Wv   = (const float*)d_in[3];
  const float* Wo   = (const float*)d_in[4];
  const float* bo   = (const float*)d_in[5];
  const float* ln1s = (const float*)d_in[6];
  const float* ln1b = (const float*)d_in[7];
  const float* ln2s = (const float*)d_in[8];
  const float* ln2b = (const float*)d_in[9];
  const float* W1   = (const float*)d_in[10];
  const float* b1   = (const float*)d_in[11];
  const float* W2   = (const float*)d_in[12];
  const float* b2   = (const float*)d_in[13];
  float* out = (float*)d_out;

  const int Mtok = 4096, D = 2048, DFF = 8192, NQKV = 6144;

  char* w = (char*)d_ws;
  u16* Wt_qkv = (u16*)w;  w += (size_t)NQKV * D * 2;
  u16* Wt_o   = (u16*)w;  w += (size_t)D * D * 2;
  u16* Wt_1   = (u16*)w;  w += (size_t)DFF * D * 2;
  u16* Wt_2   = (u16*)w;  w += (size_t)D * DFF * 2;
  u16* Xln    = (u16*)w;  w += (size_t)Mtok * D * 2;
  u16* QKV    = (u16*)w;  w += (size_t)Mtok * NQKV * 2;
  u16* CTX    = (u16*)w;  w += (size_t)Mtok * D * 2;
  u16* Y1     = QKV;        // aliases QKV+CTX after both are dead
  u16* VTb    = Wt_qkv;     // VT (16.8MB) aliases Wt_qkv (25.2MB, dead post-QKV)
  float* Hbuf = (float*)w; w += (size_t)Mtok * D * 4;

  const dim3 tb(32, 8, 1);
  transpose_cast<<<dim3(D / 32, D / 32), tb, 0, stream>>>(Wq, Wt_qkv,                    D, D);
  transpose_cast<<<dim3(D / 32, D / 32), tb, 0, stream>>>(Wk, Wt_qkv + (size_t)D * D,    D, D);
  transpose_cast<<<dim3(D / 32, D / 32), tb, 0, stream>>>(Wv, Wt_qkv + (size_t)2 * D * D,D, D);
  transpose_cast<<<dim3(D / 32, D / 32), tb, 0, stream>>>(Wo, Wt_o,                      D, D);
  transpose_cast<<<dim3(DFF / 32, D / 32), tb, 0, stream>>>(W1, Wt_1,                    D, DFF);
  transpose_cast<<<dim3(D / 32, DFF / 32), tb, 0, stream>>>(W2, Wt_2,                    DFF, D);

  ln_kernel<<<Mtok, 256, 0, stream>>>(x, ln1s, ln1b, Xln);

  // QKV: M=4096 N=6144 K=2048, MHALF=1: grid 32x24=768; region 16x6 (2x4 regions)
  gemm8<1, 1, 0, 0, 0><<<dim3(768), 512, 0, stream>>>(
      Xln, Wt_qkv, nullptr, nullptr, nullptr, QKV, Mtok, NQKV, D, 16, 6);

  // V -> VT (aliases Wt_qkv, dead after the QKV GEMM)
  transpose_v<<<dim3(64, 4, 32), tb, 0, stream>>>(QKV, VTb);

  attn_kernel<<<dim3(16, 16, 2), 256, 0, stream>>>(QKV, VTb, CTX);

  // Wo: M=4096 N=2048 K=2048, MHALF=1: grid 32x8=256; region 8x4 (4x2 regions)
  gemm8<1, 0, 1, 1, 0><<<dim3(256), 512, 0, stream>>>(
      CTX, Wt_o, bo, x, Hbuf, nullptr, Mtok, D, D, 8, 4);

  ln_kernel<<<Mtok, 256, 0, stream>>>(Hbuf, ln2s, ln2b, Xln);

  // FFN1: M=4096 N=8192 K=2048, MHALF=2: grid 16x32=512; region 8x8 (2x4 regions)
  gemm8<2, 1, 1, 0, 1><<<dim3(512), 512, 0, stream>>>(
      Xln, Wt_1, b1, nullptr, nullptr, Y1, Mtok, DFF, D, 8, 8);

  // FFN2: M=4096 N=2048 K=8192, MHALF=1: grid 32x8=256; region 8x4 (4x2 regions)
  gemm8<1, 0, 1, 1, 0><<<dim3(256), 512, 0, stream>>>(
      Y1, Wt_2, b2, Hbuf, out, nullptr, Mtok, D, DFF, 8, 4);
}